// Round 13
// baseline (596.231 us; speedup 1.0000x reference)
//
#include <hip/hip_runtime.h>
#include <hip/hip_bf16.h>
#include <stdint.h>

// ResRnn via first-order expansion in eps (method err ~1e-3 << 2.62):
//   tables: pi^t / pi^-t via composition doubling
//   stage1: permuted prefix sum -> U (bf16) + ULAST (fp32)  [8-deep reg-gather]
//   k_mlp : FUSED F = relu(U@W1^T+b1)@W2^T + b2
//           [M-slab 64, <=128 regs -> 2 blocks/CU, depth-3 vmcnt pipeline]
//   stage3: e-reduction as register gather with inverse table [8-deep]
//   final : exact fp32 last step (+ fused s3b column-sum/gather).

#define T_STEPS 2048
#define BATCH 64
#define IN_W 256
#define SW 512
#define EPS 1e-5f
#define NCHUNK 64
#define CLEN 32
#define QSTEP 32
#define NQ 65

typedef __bf16 bf16x8 __attribute__((ext_vector_type(8)));
typedef float f32x4 __attribute__((ext_vector_type(4)));

__device__ __forceinline__ unsigned short bf16bits(float v) {
  __hip_bfloat16 h = __float2bfloat16(v);
  return *reinterpret_cast<unsigned short*>(&h);
}

__device__ __forceinline__ float bf16val(unsigned short u) {
  unsigned int x = ((unsigned int)u) << 16;
  return __uint_as_float(x);
}

__device__ __forceinline__ void gload_lds16(const void* g, const void* l) {
  __builtin_amdgcn_global_load_lds(
      (const __attribute__((address_space(1))) unsigned int*)(uintptr_t)g,
      (__attribute__((address_space(3))) unsigned int*)(uintptr_t)l, 16, 0, 0);
}

// ---------------- permutation power tables (doubling) ------------------------
__global__ __launch_bounds__(512) void k_tabA(const int* __restrict__ perm,
                                              int* __restrict__ FW, int* __restrict__ IDXI) {
  __shared__ int pl[SW], il[SW];
  int j = threadIdx.x;
  pl[j] = perm[j];
  __syncthreads();
  il[pl[j]] = j;
  __syncthreads();
  int f = j, iv = j;
  FW[j] = f; IDXI[j] = iv;
  for (int t = 1; t <= QSTEP; ++t) {
    f = pl[f]; iv = il[iv];
    FW[t * SW + j] = f; IDXI[t * SW + j] = iv;
  }
}

__global__ __launch_bounds__(512) void k_tabB(const int* __restrict__ FW, const int* __restrict__ IDXI,
                                              int* __restrict__ FWQ, int* __restrict__ IDXIQ) {
  __shared__ int f32r[SW], i32r[SW];
  int j = threadIdx.x;
  f32r[j] = FW[QSTEP * SW + j];
  i32r[j] = IDXI[QSTEP * SW + j];
  __syncthreads();
  int f = j, iv = j;
  FWQ[j] = f; IDXIQ[j] = iv;
  for (int q = 1; q < NQ; ++q) {
    f = f32r[f]; iv = i32r[iv];
    FWQ[q * SW + j] = f; IDXIQ[q * SW + j] = iv;
  }
}

__global__ __launch_bounds__(512) void k_tabC(const int* __restrict__ FWQ, const int* __restrict__ IDXIQ,
                                              int* __restrict__ FW, int* __restrict__ IDXI) {
  int t = blockIdx.x;
  if (t <= QSTEP) return;
  int j = threadIdx.x;
  int q = t >> 5, r = t & 31;
  int a = FW[r * SW + j];
  FW[(size_t)t * SW + j] = FWQ[q * SW + a];
  int b = IDXI[r * SW + j];
  IDXI[(size_t)t * SW + j] = IDXIQ[q * SW + b];
}

// ---------------- weights -> bf16 --------------------------------------------
__global__ __launch_bounds__(256) void k_wcast(const float* __restrict__ W1,
                                               const float* __restrict__ W2,
                                               __hip_bfloat16* __restrict__ W1b,
                                               __hip_bfloat16* __restrict__ W2b) {
  int i = blockIdx.x * 256 + threadIdx.x;
  if (i < SW * SW) W1b[i] = __float2bfloat16(W1[i]);
  else W2b[i - SW * SW] = __float2bfloat16(W2[i - SW * SW]);
}

// ---------------- stage 1a: chunk sums, 8-deep staged register gather --------
__global__ __launch_bounds__(512) void k_s1a(const float* __restrict__ x,
                                             const int* __restrict__ IDXI,
                                             float* __restrict__ P1) {
  __shared__ float xs[8][IN_W] __attribute__((aligned(16)));
  int c = blockIdx.x, b = blockIdx.y, tid = threadIdx.x;
  const int r = tid >> 6;
  const int colx = (tid & 63) * 4;
  float acc = 0.f;
  int t0 = c * CLEN;
  for (int tt = 0; tt < CLEN; tt += 8) {
    *reinterpret_cast<f32x4*>(&xs[r][colx]) =
        *reinterpret_cast<const f32x4*>(&x[((size_t)(t0 + tt + r) * BATCH + b) * IN_W + colx]);
    __syncthreads();
#pragma unroll
    for (int k = 0; k < 8; ++k) {
      int i0 = IDXI[(size_t)(t0 + tt + k) * SW + tid];
      if (i0 < IN_W) acc += xs[k][i0];
    }
    __syncthreads();
  }
  P1[((size_t)c * BATCH + b) * SW + tid] = acc;
}

// ---------------- stage 1b: chunk scan, 16-deep batched loads ----------------
__global__ __launch_bounds__(512) void k_s1b(const float* __restrict__ init,
                                             float* __restrict__ P1) {
  int b = blockIdx.x, i = threadIdx.x;
  float run = EPS * init[i];
  float v[16];
  for (int g = 0; g < NCHUNK / 16; ++g) {
#pragma unroll
    for (int k = 0; k < 16; ++k)
      v[k] = P1[((size_t)(g * 16 + k) * BATCH + b) * SW + i];
#pragma unroll
    for (int k = 0; k < 16; ++k) {
      P1[((size_t)(g * 16 + k) * BATCH + b) * SW + i] = run;
      run += v[k];
    }
  }
}

// ---------------- stage 1c: prefix walk, 8-deep staging, coalesced U dump ----
__global__ __launch_bounds__(512) void k_s1c(const float* __restrict__ x,
                                             const int* __restrict__ IDXI,
                                             const float* __restrict__ P1,
                                             __hip_bfloat16* __restrict__ U,
                                             float* __restrict__ ULAST) {
  __shared__ float xs[8][IN_W] __attribute__((aligned(16)));
  __shared__ unsigned short us[8][SW] __attribute__((aligned(16)));
  __shared__ float ul[SW] __attribute__((aligned(16)));
  int c = blockIdx.x, b = blockIdx.y, tid = threadIdx.x;
  float v = P1[((size_t)c * BATCH + b) * SW + tid];
  int t0 = c * CLEN;
  const int r = tid >> 6;
  const int colx = (tid & 63) * 4;
  const int colu = (tid & 63) * 8;
  for (int tt = 0; tt < CLEN; tt += 8) {
    *reinterpret_cast<f32x4*>(&xs[r][colx]) =
        *reinterpret_cast<const f32x4*>(&x[((size_t)(t0 + tt + r) * BATCH + b) * IN_W + colx]);
    __syncthreads();
#pragma unroll
    for (int k = 0; k < 8; ++k) {
      int t = t0 + tt + k;
      int i0 = IDXI[(size_t)t * SW + tid];
      int i1 = IDXI[(size_t)(t + 1) * SW + tid];
      if (i0 < IN_W) v += xs[k][i0];
      us[k][i1] = bf16bits(v);
      if (t == T_STEPS - 1) ul[i1] = v;
    }
    __syncthreads();
    *reinterpret_cast<int4*>(&U[((size_t)(t0 + tt + r) * BATCH + b) * SW + colu]) =
        *reinterpret_cast<const int4*>(&us[r][colu]);
    __syncthreads();
  }
  if (c == NCHUNK - 1) ULAST[(size_t)b * SW + tid] = ul[tid];
}

// ---------------- FUSED MLP: M-slab 64, 2 blocks/CU --------------------------
// 512 thr (8 waves, grid 2x4, 32x32 wave tiles both phases). LDS 72KB (bytes):
//   phase 1: A bufs x3 [0,24K) (8K ea) | W1 bufs x3 [24K,72K) (16K ea)
//   phase 2: Hs [0,16K) | W2 bufs x3 [24K,72K)
//   epilogue: scratch [0,64K)
// Pipelines: phase 1 depth-3 vmcnt(3) (3 loads/stage); phase 2 vmcnt(2).
__global__ __launch_bounds__(512, 4) void k_mlp(const __hip_bfloat16* __restrict__ A,
                                                const __hip_bfloat16* __restrict__ W1,
                                                const __hip_bfloat16* __restrict__ W2,
                                                const float* __restrict__ b1,
                                                const float* __restrict__ b2,
                                                __hip_bfloat16* __restrict__ Fout) {
  __shared__ unsigned short smem[36864] __attribute__((aligned(16)));  // 72 KB
  const int tid = threadIdx.x;
  const int lane = tid & 63;
  const int wv = tid >> 6;
  const int wr = wv >> 2, wc = wv & 3;     // 2x4 wave grid, 32x32 tiles
  const size_t m0 = (size_t)blockIdx.x * 64;

  unsigned short* Hs = smem;               // phase-2 H tile [64][128] at byte 0

  f32x4 Facc[4][2][2];                     // [nh quarter][m][n] = 64 regs
#pragma unroll
  for (int q = 0; q < 4; ++q)
#pragma unroll
    for (int m = 0; m < 2; ++m)
#pragma unroll
      for (int n = 0; n < 2; ++n) Facc[q][m][n] = (f32x4)0.f;

  for (int hb = 0; hb < 4; ++hb) {
    f32x4 Hacc[2][2];
#pragma unroll
    for (int m = 0; m < 2; ++m)
#pragma unroll
      for (int n = 0; n < 2; ++n) Hacc[m][n] = (f32x4)0.f;

    // ---- phase 1: H(:, hb*128..+128) over K=512, depth-3 (3 loads/stage) ----
    auto stage1 = [&](int kt, int buf) {
      {
        int idx = tid;                      // A: 512 granules (64 rows x 8)
        int row = idx >> 3, pg = idx & 7;
        int sg = pg ^ (row & 7);
        gload_lds16(A + (m0 + row) * 512 + kt * 64 + sg * 8,
                    (const char*)smem + buf * 8192 + idx * 16);
      }
#pragma unroll
      for (int s = 0; s < 2; ++s) {         // W1: 1024 granules (128 rows x 8)
        int idx = s * 512 + tid;
        int row = idx >> 3, pg = idx & 7;
        int sg = pg ^ (row & 7);
        gload_lds16(W1 + (size_t)(hb * 128 + row) * 512 + kt * 64 + sg * 8,
                    (const char*)smem + 24576 + buf * 16384 + idx * 16);
      }
    };
    stage1(0, 0);
    stage1(1, 1);
#pragma unroll
    for (int kt = 0; kt < 8; ++kt) {
      if (kt < 7) asm volatile("s_waitcnt vmcnt(3)" ::: "memory");
      else        asm volatile("s_waitcnt vmcnt(0)" ::: "memory");
      __builtin_amdgcn_s_barrier();
      if (kt < 6) stage1(kt + 2, (kt + 2) % 3);  // writes buf (kt-1)%3: readers done
      const int buf = kt % 3;
      const unsigned short* Ab = smem + buf * 4096;
      const unsigned short* W1b_ = smem + 12288 + buf * 8192;
#pragma unroll
      for (int kh = 0; kh < 2; ++kh) {
        bf16x8 af[2], bfw[2];
#pragma unroll
        for (int m = 0; m < 2; ++m) {
          int row = wr * 32 + m * 16 + (lane & 15);     // 0..63
          int lg = kh * 4 + (lane >> 4);
          int phys = lg ^ (row & 7);
          af[m] = *reinterpret_cast<const bf16x8*>(&Ab[row * 64 + phys * 8]);
        }
#pragma unroll
        for (int n = 0; n < 2; ++n) {
          int row = wc * 32 + n * 16 + (lane & 15);     // 0..127 (H cols)
          int lg = kh * 4 + (lane >> 4);
          int phys = lg ^ (row & 7);
          bfw[n] = *reinterpret_cast<const bf16x8*>(&W1b_[row * 64 + phys * 8]);
        }
#pragma unroll
        for (int m = 0; m < 2; ++m)
#pragma unroll
          for (int n = 0; n < 2; ++n)
            Hacc[m][n] = __builtin_amdgcn_mfma_f32_16x16x32_bf16(af[m], bfw[n], Hacc[m][n], 0, 0, 0);
      }
    }
    __syncthreads();  // all phase-1 LDS reads done before region reuse

    // issue W2 round-0 tile (nh=0,ks=0: 128 rows x 64k) into buf 0 [24K,40K)
    {
#pragma unroll
      for (int s = 0; s < 2; ++s) {
        int idx = s * 512 + tid;
        int row = idx >> 3, pg = idx & 7;
        int sg = pg ^ (row & 7);
        gload_lds16(W2 + (size_t)row * 512 + hb * 128 + sg * 8,
                    (const char*)smem + 24576 + idx * 16);
      }
    }

    // Hacc + b1 -> relu -> Hs [64][128], swizzled 16-granule period-16
    {
      const int rl = (lane >> 4) * 4;
      const int cl = lane & 15;
#pragma unroll
      for (int m = 0; m < 2; ++m)
#pragma unroll
        for (int n = 0; n < 2; ++n) {
          int coll = wc * 32 + n * 16 + cl;             // 0..127
          float bv = b1[hb * 128 + coll];
#pragma unroll
          for (int r = 0; r < 4; ++r) {
            int rowl = wr * 32 + m * 16 + rl + r;       // 0..63
            float h = Hacc[m][n][r] + bv;
            h = h > 0.f ? h : 0.f;
            int phys = (coll >> 3) ^ (rowl & 15);
            Hs[rowl * 128 + phys * 8 + (coll & 7)] = bf16bits(h);
          }
        }
    }
    __syncthreads();  // drains W2 round-0 staging + Hs writes

    // ---- phase 2: 8 rounds r=(nh=r>>1, ks=r&1), W2 triple-buffer ----
#pragma unroll
    for (int r = 0; r < 8; ++r) {
      if (r < 7) {
        int rn = r + 1;
        int nhn = rn >> 1, ksn = rn & 1;
        int regbyte = 24576 + (rn % 3) * 16384;
#pragma unroll
        for (int s = 0; s < 2; ++s) {
          int idx = s * 512 + tid;
          int row = idx >> 3, pg = idx & 7;
          int sg = pg ^ (row & 7);
          gload_lds16(W2 + (size_t)(nhn * 128 + row) * 512 + hb * 128 + ksn * 64 + sg * 8,
                      (const char*)smem + regbyte + idx * 16);
        }
      }
      if (r > 0) {
        if (r < 7) asm volatile("s_waitcnt vmcnt(2)" ::: "memory");
        else       asm volatile("s_waitcnt vmcnt(0)" ::: "memory");
        __builtin_amdgcn_s_barrier();
      }
      const int nh = r >> 1, ks = r & 1;
      const unsigned short* w2b = smem + 12288 + (r % 3) * 8192;  // ushort off
#pragma unroll
      for (int kh = 0; kh < 2; ++kh) {
        bf16x8 afH[2], bf2[2];
#pragma unroll
        for (int m = 0; m < 2; ++m) {
          int row = wr * 32 + m * 16 + (lane & 15);     // H rows 0..63
          int hg = ks * 8 + kh * 4 + (lane >> 4);       // k-granule 0..15
          int phys = hg ^ (row & 15);
          afH[m] = *reinterpret_cast<const bf16x8*>(&Hs[row * 128 + phys * 8]);
        }
#pragma unroll
        for (int n = 0; n < 2; ++n) {
          int row = wc * 32 + n * 16 + (lane & 15);     // N within nh: 0..127
          int lg = kh * 4 + (lane >> 4);
          int phys = lg ^ (row & 7);
          bf2[n] = *reinterpret_cast<const bf16x8*>(&w2b[row * 64 + phys * 8]);
        }
#pragma unroll
        for (int m = 0; m < 2; ++m)
#pragma unroll
          for (int n = 0; n < 2; ++n)
            Facc[nh][m][n] = __builtin_amdgcn_mfma_f32_16x16x32_bf16(afH[m], bf2[n], Facc[nh][m][n], 0, 0, 0);
      }
    }
    __syncthreads();  // phase-2 reads done before next hb stage1 / epilogue
  }

  // ---- F epilogue: Facc + b2 -> scratch [64][512] swizzled -> int4 stores ----
  {
    const int rl = (lane >> 4) * 4;
    const int cl = lane & 15;
#pragma unroll
    for (int q = 0; q < 4; ++q)
#pragma unroll
      for (int m = 0; m < 2; ++m)
#pragma unroll
        for (int n = 0; n < 2; ++n) {
          int coll = q * 128 + wc * 32 + n * 16 + cl;   // 0..511
          float bv = b2[coll];
#pragma unroll
          for (int r = 0; r < 4; ++r) {
            int rowl = wr * 32 + m * 16 + rl + r;       // 0..63
            float v = Facc[q][m][n][r] + bv;
            int phys = (coll >> 3) ^ (rowl & 31);       // 64 granules/row
            smem[rowl * 512 + phys * 8 + (coll & 7)] = bf16bits(v);
          }
        }
    __syncthreads();
#pragma unroll
    for (int s = 0; s < 8; ++s) {
      int idx = s * 512 + tid;                          // 4096 granules
      int rowl = idx >> 6, g = idx & 63;
      int phys = g ^ (rowl & 31);
      *reinterpret_cast<int4*>(Fout + (m0 + rowl) * 512 + g * 8) =
          *reinterpret_cast<const int4*>(&smem[rowl * 512 + phys * 8]);
    }
  }
}

// ---------------- stage 3a: 8-deep staged register gather --------------------
__global__ __launch_bounds__(512) void k_s3a(const __hip_bfloat16* __restrict__ F,
                                             const int* __restrict__ IDXI,
                                             float* __restrict__ P3) {
  __shared__ unsigned short fs[8][SW] __attribute__((aligned(16)));
  int c = blockIdx.x, b = blockIdx.y, tid = threadIdx.x;
  const int r = tid >> 6;
  const int colf = (tid & 63) * 8;
  float acc = 0.f;
  int t0 = c * CLEN;
  for (int tt = 0; tt < CLEN; tt += 8) {
    *reinterpret_cast<int4*>(&fs[r][colf]) =
        *reinterpret_cast<const int4*>(&F[((size_t)(t0 + tt + r) * BATCH + b) * SW + colf]);
    __syncthreads();
#pragma unroll
    for (int k = 0; k < 8; ++k) {
      int t = t0 + tt + k;
      if (t < T_STEPS - 1) {
        int i0 = IDXI[(size_t)t * SW + tid];
        acc += bf16val(fs[k][i0]);
      }
    }
    __syncthreads();
  }
  P3[((size_t)c * BATCH + b) * SW + tid] = acc;
}

// ---------------- exact fp32 final step (+ fused s3b), r11 version -----------
__global__ __launch_bounds__(512) void k_final(const float* __restrict__ P3,
                                               const int* __restrict__ FW,
                                               const float* __restrict__ ULAST,
                                               const float* __restrict__ W1,
                                               const float* __restrict__ b1,
                                               const float* __restrict__ W2,
                                               const float* __restrict__ b2,
                                               float* __restrict__ out) {
  __shared__ float ml[SW] __attribute__((aligned(16)));
  __shared__ float uc[SW] __attribute__((aligned(16)));
  __shared__ float hh[SW] __attribute__((aligned(16)));
  int b = blockIdx.x, j = threadIdx.x;
  float s = 0.f;
  for (int c = 0; c < NCHUNK; ++c) s += P3[((size_t)c * BATCH + b) * SW + j];
  ml[j] = s;
  __syncthreads();
  float e = ml[FW[(size_t)(T_STEPS - 1) * SW + j]];
  float u = ULAST[(size_t)b * SW + j] + EPS * e;
  uc[j] = u;
  __syncthreads();
  float pre = b1[j];
  {
    const f32x4* wr = (const f32x4*)(W1 + (size_t)j * SW);
    const f32x4* uv = (const f32x4*)uc;
    for (int k = 0; k < SW / 4; ++k) {
      f32x4 wv = wr[k], vv = uv[k];
      pre += wv[0] * vv[0] + wv[1] * vv[1] + wv[2] * vv[2] + wv[3] * vv[3];
    }
  }
  hh[j] = pre > 0.f ? pre : 0.f;
  __syncthreads();
  float d = b2[j];
  {
    const f32x4* wr = (const f32x4*)(W2 + (size_t)j * SW);
    const f32x4* hv = (const f32x4*)hh;
    for (int k = 0; k < SW / 4; ++k) {
      f32x4 wv = wr[k], vv = hv[k];
      d += wv[0] * vv[0] + wv[1] * vv[1] + wv[2] * vv[2] + wv[3] * vv[3];
    }
  }
  float sT = u + EPS * d;
  out[BATCH * 128 + (size_t)b * SW + j] = sT;                // last  [64,512]
  if (j >= SW - 128) out[b * 128 + (j - (SW - 128))] = sT;   // outputs [64,128]
}

// ---------------- host -------------------------------------------------------
extern "C" void kernel_launch(void* const* d_in, const int* in_sizes, int n_in,
                              void* d_out, int out_size, void* d_ws, size_t ws_size,
                              hipStream_t stream) {
  const float* x = (const float*)d_in[0];
  const float* init = (const float*)d_in[1];
  const float* W1 = (const float*)d_in[2];
  const float* b1 = (const float*)d_in[3];
  const float* W2 = (const float*)d_in[4];
  const float* b2 = (const float*)d_in[5];
  const int* perm = (const int*)d_in[6];
  float* out = (float*)d_out;

  char* w = (char*)d_ws;
  size_t off = 0;
  auto alloc = [&](size_t bytes) {
    size_t o = off;
    off = (off + bytes + 255) & ~(size_t)255;
    return o;
  };
  size_t oFW   = alloc((size_t)(T_STEPS + 1) * SW * 4);
  size_t oIDXI = alloc((size_t)(T_STEPS + 1) * SW * 4);
  size_t oFWQ  = alloc((size_t)NQ * SW * 4);
  size_t oIDXQ = alloc((size_t)NQ * SW * 4);
  size_t oW1b  = alloc((size_t)SW * SW * 2);
  size_t oW2b  = alloc((size_t)SW * SW * 2);
  size_t oU    = alloc((size_t)T_STEPS * BATCH * SW * 2);  // aliased as F
  size_t oP1   = alloc((size_t)NCHUNK * BATCH * SW * 4);
  size_t oP3   = alloc((size_t)NCHUNK * BATCH * SW * 4);
  size_t oUL   = alloc((size_t)BATCH * SW * 4);
  if (off > ws_size) return;

  int* FW = (int*)(w + oFW);
  int* IDXI = (int*)(w + oIDXI);
  int* FWQ = (int*)(w + oFWQ);
  int* IDXIQ = (int*)(w + oIDXQ);
  __hip_bfloat16* W1b = (__hip_bfloat16*)(w + oW1b);
  __hip_bfloat16* W2b = (__hip_bfloat16*)(w + oW2b);
  __hip_bfloat16* U = (__hip_bfloat16*)(w + oU);
  float* P1 = (float*)(w + oP1);
  float* P3 = (float*)(w + oP3);
  float* ULAST = (float*)(w + oUL);

  k_tabA<<<1, 512, 0, stream>>>(perm, FW, IDXI);
  k_tabB<<<1, 512, 0, stream>>>(FW, IDXI, FWQ, IDXIQ);
  k_tabC<<<T_STEPS + 1, 512, 0, stream>>>(FWQ, IDXIQ, FW, IDXI);
  k_wcast<<<(2 * SW * SW + 255) / 256, 256, 0, stream>>>(W1, W2, W1b, W2b);

  k_s1a<<<dim3(NCHUNK, BATCH), 512, 0, stream>>>(x, IDXI, P1);
  k_s1b<<<BATCH, 512, 0, stream>>>(init, P1);
  k_s1c<<<dim3(NCHUNK, BATCH), 512, 0, stream>>>(x, IDXI, P1, U, ULAST);

  k_mlp<<<(T_STEPS * BATCH) / 64, 512, 0, stream>>>(U, W1b, W2b, b1, b2, U);

  k_s3a<<<dim3(NCHUNK, BATCH), 512, 0, stream>>>(U, IDXI, P3);

  k_final<<<BATCH, 512, 0, stream>>>(P3, FW, ULAST, W1, b1, W2, b2, out);
}

// Round 14
// 501.145 us; speedup vs baseline: 1.1897x; 1.1897x over previous
//
#include <hip/hip_runtime.h>
#include <hip/hip_bf16.h>
#include <stdint.h>

// ResRnn via first-order expansion in eps (method err ~1e-3 << 2.62):
//   tables: pi^t / pi^-t via composition doubling
//   stage1: permuted prefix sum -> U (fp8 e4m3) + ULAST (fp32)
//   k_mlp : FUSED F = relu(U@W1^T+b1)@W2^T + b2, ALL-fp8 operands (r11
//           structure: depth-3 counted-vmcnt phase 1, tri-buffered phase 2)
//   stage3: e-reduction register gather (F in bf16, unchanged)
//   final : exact fp32 last step (+ fused s3b).

#define T_STEPS 2048
#define BATCH 64
#define IN_W 256
#define SW 512
#define EPS 1e-5f
#define NCHUNK 64
#define CLEN 32
#define QSTEP 32
#define NQ 65

typedef float f32x4 __attribute__((ext_vector_type(4)));

__device__ __forceinline__ unsigned short bf16bits(float v) {
  __hip_bfloat16 h = __float2bfloat16(v);
  return *reinterpret_cast<unsigned short*>(&h);
}

__device__ __forceinline__ float bf16val(unsigned short u) {
  unsigned int x = ((unsigned int)u) << 16;
  return __uint_as_float(x);
}

// float -> OCP e4m3 (RNE, clamp +-448, flush |x|<2^-6 to 0; no denormals)
__device__ __forceinline__ unsigned char f32_to_e4m3(float f) {
  unsigned char sign = (__float_as_uint(f) >> 24) & 0x80u;
  float a = fabsf(f);
  if (a < 0.015625f) return sign;
  if (a > 448.f) a = 448.f;
  int e;
  (void)frexpf(a, &e);                         // a = m*2^e, m in [.5,1)
  float q = ldexpf(rintf(ldexpf(a, 4 - e)), e - 4);  // ulp = 2^(e-4)
  unsigned int qu = __float_as_uint(q);
  int qe = (int)((qu >> 23) & 0xFF) - 127;
  unsigned int qm = (qu >> 20) & 0x7;
  return sign | (unsigned char)(((qe + 7) << 3) | qm);
}

__device__ __forceinline__ void gload_lds16(const void* g, const void* l) {
  __builtin_amdgcn_global_load_lds(
      (const __attribute__((address_space(1))) unsigned int*)(uintptr_t)g,
      (__attribute__((address_space(3))) unsigned int*)(uintptr_t)l, 16, 0, 0);
}

// ---------------- permutation power tables (doubling) ------------------------
__global__ __launch_bounds__(512) void k_tabA(const int* __restrict__ perm,
                                              int* __restrict__ FW, int* __restrict__ IDXI) {
  __shared__ int pl[SW], il[SW];
  int j = threadIdx.x;
  pl[j] = perm[j];
  __syncthreads();
  il[pl[j]] = j;
  __syncthreads();
  int f = j, iv = j;
  FW[j] = f; IDXI[j] = iv;
  for (int t = 1; t <= QSTEP; ++t) {
    f = pl[f]; iv = il[iv];
    FW[t * SW + j] = f; IDXI[t * SW + j] = iv;
  }
}

__global__ __launch_bounds__(512) void k_tabB(const int* __restrict__ FW, const int* __restrict__ IDXI,
                                              int* __restrict__ FWQ, int* __restrict__ IDXIQ) {
  __shared__ int f32r[SW], i32r[SW];
  int j = threadIdx.x;
  f32r[j] = FW[QSTEP * SW + j];
  i32r[j] = IDXI[QSTEP * SW + j];
  __syncthreads();
  int f = j, iv = j;
  FWQ[j] = f; IDXIQ[j] = iv;
  for (int q = 1; q < NQ; ++q) {
    f = f32r[f]; iv = i32r[iv];
    FWQ[q * SW + j] = f; IDXIQ[q * SW + j] = iv;
  }
}

__global__ __launch_bounds__(512) void k_tabC(const int* __restrict__ FWQ, const int* __restrict__ IDXIQ,
                                              int* __restrict__ FW, int* __restrict__ IDXI) {
  int t = blockIdx.x;
  if (t <= QSTEP) return;
  int j = threadIdx.x;
  int q = t >> 5, r = t & 31;
  int a = FW[r * SW + j];
  FW[(size_t)t * SW + j] = FWQ[q * SW + a];
  int b = IDXI[r * SW + j];
  IDXI[(size_t)t * SW + j] = IDXIQ[q * SW + b];
}

// ---------------- weights -> fp8 ---------------------------------------------
__global__ __launch_bounds__(256) void k_wcast(const float* __restrict__ W1,
                                               const float* __restrict__ W2,
                                               unsigned char* __restrict__ W1q,
                                               unsigned char* __restrict__ W2q) {
  int i = blockIdx.x * 256 + threadIdx.x;
  if (i < SW * SW) W1q[i] = f32_to_e4m3(W1[i]);
  else W2q[i - SW * SW] = f32_to_e4m3(W2[i - SW * SW]);
}

// ---------------- stage 1a: chunk sums, 8-deep staged register gather --------
__global__ __launch_bounds__(512) void k_s1a(const float* __restrict__ x,
                                             const int* __restrict__ IDXI,
                                             float* __restrict__ P1) {
  __shared__ float xs[8][IN_W] __attribute__((aligned(16)));
  int c = blockIdx.x, b = blockIdx.y, tid = threadIdx.x;
  const int r = tid >> 6;
  const int colx = (tid & 63) * 4;
  float acc = 0.f;
  int t0 = c * CLEN;
  for (int tt = 0; tt < CLEN; tt += 8) {
    *reinterpret_cast<f32x4*>(&xs[r][colx]) =
        *reinterpret_cast<const f32x4*>(&x[((size_t)(t0 + tt + r) * BATCH + b) * IN_W + colx]);
    __syncthreads();
#pragma unroll
    for (int k = 0; k < 8; ++k) {
      int i0 = IDXI[(size_t)(t0 + tt + k) * SW + tid];
      if (i0 < IN_W) acc += xs[k][i0];
    }
    __syncthreads();
  }
  P1[((size_t)c * BATCH + b) * SW + tid] = acc;
}

__global__ __launch_bounds__(512) void k_s1b(const float* __restrict__ init,
                                             float* __restrict__ P1) {
  int b = blockIdx.x, i = threadIdx.x;
  float run = EPS * init[i];
  for (int c = 0; c < NCHUNK; ++c) {
    size_t o = ((size_t)c * BATCH + b) * SW + i;
    float t = P1[o]; P1[o] = run; run += t;
  }
}

// ---------------- stage 1c: prefix walk -> fp8 U + fp32 ULAST ----------------
__global__ __launch_bounds__(512) void k_s1c(const float* __restrict__ x,
                                             const int* __restrict__ IDXI,
                                             const float* __restrict__ P1,
                                             unsigned char* __restrict__ U,
                                             float* __restrict__ ULAST) {
  __shared__ float xs[8][IN_W] __attribute__((aligned(16)));
  __shared__ unsigned char us[8][SW] __attribute__((aligned(16)));
  __shared__ float ul[SW] __attribute__((aligned(16)));
  int c = blockIdx.x, b = blockIdx.y, tid = threadIdx.x;
  float v = P1[((size_t)c * BATCH + b) * SW + tid];
  int t0 = c * CLEN;
  const int r = tid >> 6;
  const int colx = (tid & 63) * 4;
  for (int tt = 0; tt < CLEN; tt += 8) {
    *reinterpret_cast<f32x4*>(&xs[r][colx]) =
        *reinterpret_cast<const f32x4*>(&x[((size_t)(t0 + tt + r) * BATCH + b) * IN_W + colx]);
    __syncthreads();
#pragma unroll
    for (int k = 0; k < 8; ++k) {
      int t = t0 + tt + k;
      int i0 = IDXI[(size_t)t * SW + tid];
      int i1 = IDXI[(size_t)(t + 1) * SW + tid];
      if (i0 < IN_W) v += xs[k][i0];
      us[k][i1] = f32_to_e4m3(v);
      if (t == T_STEPS - 1) ul[i1] = v;
    }
    __syncthreads();
    if (tid < 256) {   // 8 rows x 32 granules of 16B
      int row = tid >> 5, g = tid & 31;
      *reinterpret_cast<int4*>(U + ((size_t)(t0 + tt + row) * BATCH + b) * SW + g * 16) =
          *reinterpret_cast<const int4*>(&us[row][g * 16]);
    }
    __syncthreads();
  }
  if (c == NCHUNK - 1) ULAST[(size_t)b * SW + tid] = ul[tid];
}

// ---------------- FUSED MLP, all-fp8 operands --------------------------------
// 512 thr (8 waves), M-slab 128. LDS 112KB (bytes):
//   A bufs x3   [0,24K)     (8K each, 128x64 fp8)
//   W1 bufs x3  [24K,48K)   (8K each)
//   W2 bufs x3  [48K,96K)   (16K each, 256x64 fp8)
//   Hs          [96K,112K)  (128x128 fp8, 8B-granule swizzled)
//   epilogue scratch reuses [0,64K)
// 16B source-granule swizzle sg = pg^(row&3); reads via b64 with matching
// phys = ((g>>1)^(row&3))*16 + (g&1)*8.
__global__ __launch_bounds__(512, 2) void k_mlp(const unsigned char* __restrict__ A,
                                                const unsigned char* __restrict__ W1,
                                                const unsigned char* __restrict__ W2,
                                                const float* __restrict__ b1,
                                                const float* __restrict__ b2,
                                                __hip_bfloat16* __restrict__ Fout) {
  __shared__ unsigned char smem[114688] __attribute__((aligned(16)));
  const int tid = threadIdx.x;
  const int lane = tid & 63;
  const int wv = tid >> 6;
  const int hwr = wv >> 1, hwc = wv & 1;   // phase-1 grid 4x2 (32x64 tiles)
  const int fwr = wv >> 2, fwc = wv & 3;   // phase-2 grid 2x4 (64x128 tiles)
  const size_t m0 = (size_t)blockIdx.x * 128;
  unsigned char* Hs = smem + 98304;

  f32x4 Facc[2][4][4];
#pragma unroll
  for (int nh = 0; nh < 2; ++nh)
#pragma unroll
    for (int m = 0; m < 4; ++m)
#pragma unroll
      for (int n = 0; n < 4; ++n) Facc[nh][m][n] = (f32x4)0.f;

  for (int hb = 0; hb < 4; ++hb) {
    f32x4 Hacc[2][4];
#pragma unroll
    for (int m = 0; m < 2; ++m)
#pragma unroll
      for (int n = 0; n < 4; ++n) Hacc[m][n] = (f32x4)0.f;

    // ---- phase 1: depth-3 pipeline, 2 loads/thread/stage ----
    auto stage1 = [&](int kt, int buf) {
      int row = tid >> 2, pg = tid & 3;
      int sg = pg ^ (row & 3);
      gload_lds16(A + (m0 + row) * 512 + kt * 64 + sg * 16,
                  (const char*)smem + buf * 8192 + tid * 16);
      gload_lds16(W1 + (size_t)(hb * 128 + row) * 512 + kt * 64 + sg * 16,
                  (const char*)smem + 24576 + buf * 8192 + tid * 16);
    };
    stage1(0, 0);
    stage1(1, 1);
#pragma unroll
    for (int kt = 0; kt < 8; ++kt) {
      if (kt < 7) asm volatile("s_waitcnt vmcnt(2)" ::: "memory");
      else        asm volatile("s_waitcnt vmcnt(0)" ::: "memory");
      __builtin_amdgcn_s_barrier();
      if (kt < 6) stage1(kt + 2, (kt + 2) % 3);
      const unsigned char* Ab = smem + (kt % 3) * 8192;
      const unsigned char* W1b_ = smem + 24576 + (kt % 3) * 8192;
#pragma unroll
      for (int kh = 0; kh < 2; ++kh) {
        long af[2], bfw[4];
        int g = kh * 4 + (lane >> 4);
#pragma unroll
        for (int m = 0; m < 2; ++m) {
          int row = hwr * 32 + m * 16 + (lane & 15);
          int off = row * 64 + ((((g >> 1) ^ (row & 3)) << 4) | ((g & 1) << 3));
          af[m] = *reinterpret_cast<const long*>(Ab + off);
        }
#pragma unroll
        for (int n = 0; n < 4; ++n) {
          int row = hwc * 64 + n * 16 + (lane & 15);
          int off = row * 64 + ((((g >> 1) ^ (row & 3)) << 4) | ((g & 1) << 3));
          bfw[n] = *reinterpret_cast<const long*>(W1b_ + off);
        }
#pragma unroll
        for (int m = 0; m < 2; ++m)
#pragma unroll
          for (int n = 0; n < 4; ++n)
            Hacc[m][n] = __builtin_amdgcn_mfma_f32_16x16x32_fp8_fp8(af[m], bfw[n], Hacc[m][n], 0, 0, 0);
      }
    }
    __syncthreads();  // all phase-1 LDS reads done

    // issue W2 round-0 (256 rows x 64 k fp8 = 16KB) into W2 buf 0
    {
#pragma unroll
      for (int s = 0; s < 2; ++s) {
        int idx = s * 512 + tid;
        int row = idx >> 2, pg = idx & 3;
        int sg = pg ^ (row & 3);
        gload_lds16(W2 + (size_t)row * 512 + hb * 128 + sg * 16,
                    (const char*)smem + 49152 + idx * 16);
      }
    }

    // Hacc + b1 -> relu -> fp8 Hs [128 rows][16 8B-granules], phys = hg^(row&15)
    {
      const int rl = (lane >> 4) * 4;
      const int cl = lane & 15;
#pragma unroll
      for (int m = 0; m < 2; ++m)
#pragma unroll
        for (int n = 0; n < 4; ++n) {
          int coll = hwc * 64 + n * 16 + cl;
          float bv = b1[hb * 128 + coll];
#pragma unroll
          for (int r = 0; r < 4; ++r) {
            int rowl = hwr * 32 + m * 16 + rl + r;
            float h = Hacc[m][n][r] + bv;
            h = h > 0.f ? h : 0.f;
            int phys = (coll >> 3) ^ (rowl & 15);
            Hs[rowl * 128 + phys * 8 + (coll & 7)] = f32_to_e4m3(h);
          }
        }
    }
    __syncthreads();  // drains W2 round-0 + Hs writes

    // ---- phase 2: 4 rounds, W2 tri-buffer, counted vmcnt ----
#pragma unroll
    for (int r = 0; r < 4; ++r) {
      if (r < 3) {
        int rn = r + 1;
        int ksn = rn >> 1, nhn = rn & 1;
        int regbyte = 49152 + (rn % 3) * 16384;
#pragma unroll
        for (int s = 0; s < 2; ++s) {
          int idx = s * 512 + tid;
          int row = idx >> 2, pg = idx & 3;
          int sg = pg ^ (row & 3);
          gload_lds16(W2 + (size_t)(nhn * 256 + row) * 512 + hb * 128 + ksn * 64 + sg * 16,
                      (const char*)smem + regbyte + idx * 16);
        }
      }
      if (r > 0) {
        if (r < 3) asm volatile("s_waitcnt vmcnt(2)" ::: "memory");
        else       asm volatile("s_waitcnt vmcnt(0)" ::: "memory");
        __builtin_amdgcn_s_barrier();
      }
      const int ks = r >> 1, nh = r & 1;
      const unsigned char* w2b = smem + 49152 + (r % 3) * 16384;
#pragma unroll
      for (int kh = 0; kh < 2; ++kh) {
        long afH[4], bf2[4];
        int g = kh * 4 + (lane >> 4);
#pragma unroll
        for (int m = 0; m < 4; ++m) {
          int row = fwr * 64 + m * 16 + (lane & 15);
          int hg = ks * 8 + g;                 // 0..15
          int phys = hg ^ (row & 15);
          afH[m] = *reinterpret_cast<const long*>(Hs + row * 128 + phys * 8);
        }
#pragma unroll
        for (int n = 0; n < 4; ++n) {
          int row = fwc * 64 + n * 16 + (lane & 15);
          int off = row * 64 + ((((g >> 1) ^ (row & 3)) << 4) | ((g & 1) << 3));
          bf2[n] = *reinterpret_cast<const long*>(w2b + off);
        }
#pragma unroll
        for (int m = 0; m < 4; ++m)
#pragma unroll
          for (int n = 0; n < 4; ++n)
            Facc[nh][m][n] = __builtin_amdgcn_mfma_f32_16x16x32_fp8_fp8(afH[m], bf2[n], Facc[nh][m][n], 0, 0, 0);
      }
    }
    __syncthreads();  // phase-2 LDS reads done before next hb / epilogue
  }

  // ---- F epilogue (bf16): Facc + b2 -> scratch [128][256] -> int4 stores ----
  unsigned short* sm16 = reinterpret_cast<unsigned short*>(smem);
  const int rl = (lane >> 4) * 4;
  const int cl = lane & 15;
#pragma unroll
  for (int nh = 0; nh < 2; ++nh) {
#pragma unroll
    for (int m = 0; m < 4; ++m)
#pragma unroll
      for (int n = 0; n < 4; ++n) {
        int coll = fwc * 64 + n * 16 + cl;
        float bv = b2[nh * 256 + coll];
#pragma unroll
        for (int r = 0; r < 4; ++r) {
          int rowl = fwr * 64 + m * 16 + rl + r;
          float v = Facc[nh][m][n][r] + bv;
          int phys = (coll >> 3) ^ (rowl & 31);
          sm16[rowl * 256 + phys * 8 + (coll & 7)] = bf16bits(v);
        }
      }
    __syncthreads();
#pragma unroll
    for (int s = 0; s < 8; ++s) {
      int idx = s * 512 + tid;
      int rowl = idx >> 5, g = idx & 31;
      int phys = g ^ (rowl & 31);
      *reinterpret_cast<int4*>(Fout + (m0 + rowl) * 512 + nh * 256 + g * 8) =
          *reinterpret_cast<const int4*>(&sm16[rowl * 256 + phys * 8]);
    }
    __syncthreads();
  }
}

// ---------------- stage 3a: 8-deep staged register gather (bf16 F) -----------
__global__ __launch_bounds__(512) void k_s3a(const __hip_bfloat16* __restrict__ F,
                                             const int* __restrict__ IDXI,
                                             float* __restrict__ P3) {
  __shared__ unsigned short fs[8][SW] __attribute__((aligned(16)));
  int c = blockIdx.x, b = blockIdx.y, tid = threadIdx.x;
  const int r = tid >> 6;
  const int colf = (tid & 63) * 8;
  float acc = 0.f;
  int t0 = c * CLEN;
  for (int tt = 0; tt < CLEN; tt += 8) {
    *reinterpret_cast<int4*>(&fs[r][colf]) =
        *reinterpret_cast<const int4*>(&F[((size_t)(t0 + tt + r) * BATCH + b) * SW + colf]);
    __syncthreads();
#pragma unroll
    for (int k = 0; k < 8; ++k) {
      int t = t0 + tt + k;
      if (t < T_STEPS - 1) {
        int i0 = IDXI[(size_t)t * SW + tid];
        acc += bf16val(fs[k][i0]);
      }
    }
    __syncthreads();
  }
  P3[((size_t)c * BATCH + b) * SW + tid] = acc;
}

// ---------------- exact fp32 final step (+ fused s3b) ------------------------
__global__ __launch_bounds__(512) void k_final(const float* __restrict__ P3,
                                               const int* __restrict__ FW,
                                               const float* __restrict__ ULAST,
                                               const float* __restrict__ W1,
                                               const float* __restrict__ b1,
                                               const float* __restrict__ W2,
                                               const float* __restrict__ b2,
                                               float* __restrict__ out) {
  __shared__ float ml[SW] __attribute__((aligned(16)));
  __shared__ float uc[SW] __attribute__((aligned(16)));
  __shared__ float hh[SW] __attribute__((aligned(16)));
  int b = blockIdx.x, j = threadIdx.x;
  float s = 0.f;
  for (int c = 0; c < NCHUNK; ++c) s += P3[((size_t)c * BATCH + b) * SW + j];
  ml[j] = s;
  __syncthreads();
  float e = ml[FW[(size_t)(T_STEPS - 1) * SW + j]];
  float u = ULAST[(size_t)b * SW + j] + EPS * e;
  uc[j] = u;
  __syncthreads();
  float pre = b1[j];
  {
    const f32x4* wr = (const f32x4*)(W1 + (size_t)j * SW);
    const f32x4* uv = (const f32x4*)uc;
    for (int k = 0; k < SW / 4; ++k) {
      f32x4 wv = wr[k], vv = uv[k];
      pre += wv[0] * vv[0] + wv[1] * vv[1] + wv[2] * vv[2] + wv[3] * vv[3];
    }
  }
  hh[j] = pre > 0.f ? pre : 0.f;
  __syncthreads();
  float d = b2[j];
  {
    const f32x4* wr = (const f32x4*)(W2 + (size_t)j * SW);
    const f32x4* hv = (const f32x4*)hh;
    for (int k = 0; k < SW / 4; ++k) {
      f32x4 wv = wr[k], vv = hv[k];
      d += wv[0] * vv[0] + wv[1] * vv[1] + wv[2] * vv[2] + wv[3] * vv[3];
    }
  }
  float sT = u + EPS * d;
  out[BATCH * 128 + (size_t)b * SW + j] = sT;                // last  [64,512]
  if (j >= SW - 128) out[b * 128 + (j - (SW - 128))] = sT;   // outputs [64,128]
}

// ---------------- host -------------------------------------------------------
extern "C" void kernel_launch(void* const* d_in, const int* in_sizes, int n_in,
                              void* d_out, int out_size, void* d_ws, size_t ws_size,
                              hipStream_t stream) {
  const float* x = (const float*)d_in[0];
  const float* init = (const float*)d_in[1];
  const float* W1 = (const float*)d_in[2];
  const float* b1 = (const float*)d_in[3];
  const float* W2 = (const float*)d_in[4];
  const float* b2 = (const float*)d_in[5];
  const int* perm = (const int*)d_in[6];
  float* out = (float*)d_out;

  char* w = (char*)d_ws;
  size_t off = 0;
  auto alloc = [&](size_t bytes) {
    size_t o = off;
    off = (off + bytes + 255) & ~(size_t)255;
    return o;
  };
  size_t oFW   = alloc((size_t)(T_STEPS + 1) * SW * 4);
  size_t oIDXI = alloc((size_t)(T_STEPS + 1) * SW * 4);
  size_t oFWQ  = alloc((size_t)NQ * SW * 4);
  size_t oIDXQ = alloc((size_t)NQ * SW * 4);
  size_t oW1q  = alloc((size_t)SW * SW);
  size_t oW2q  = alloc((size_t)SW * SW);
  size_t oU    = alloc((size_t)T_STEPS * BATCH * SW);      // fp8
  size_t oF    = alloc((size_t)T_STEPS * BATCH * SW * 2);  // bf16
  size_t oP1   = alloc((size_t)NCHUNK * BATCH * SW * 4);
  size_t oP3   = alloc((size_t)NCHUNK * BATCH * SW * 4);
  size_t oUL   = alloc((size_t)BATCH * SW * 4);
  if (off > ws_size) return;

  int* FW = (int*)(w + oFW);
  int* IDXI = (int*)(w + oIDXI);
  int* FWQ = (int*)(w + oFWQ);
  int* IDXIQ = (int*)(w + oIDXQ);
  unsigned char* W1q = (unsigned char*)(w + oW1q);
  unsigned char* W2q = (unsigned char*)(w + oW2q);
  unsigned char* U = (unsigned char*)(w + oU);
  __hip_bfloat16* F = (__hip_bfloat16*)(w + oF);
  float* P1 = (float*)(w + oP1);
  float* P3 = (float*)(w + oP3);
  float* ULAST = (float*)(w + oUL);

  k_tabA<<<1, 512, 0, stream>>>(perm, FW, IDXI);
  k_tabB<<<1, 512, 0, stream>>>(FW, IDXI, FWQ, IDXIQ);
  k_tabC<<<T_STEPS + 1, 512, 0, stream>>>(FWQ, IDXIQ, FW, IDXI);
  k_wcast<<<(2 * SW * SW + 255) / 256, 256, 0, stream>>>(W1, W2, W1q, W2q);

  k_s1a<<<dim3(NCHUNK, BATCH), 512, 0, stream>>>(x, IDXI, P1);
  k_s1b<<<BATCH, 512, 0, stream>>>(init, P1);
  k_s1c<<<dim3(NCHUNK, BATCH), 512, 0, stream>>>(x, IDXI, P1, U, ULAST);

  k_mlp<<<(T_STEPS * BATCH) / 128, 512, 0, stream>>>(U, W1q, W2q, b1, b2, F);

  k_s3a<<<dim3(NCHUNK, BATCH), 512, 0, stream>>>(F, IDXI, P3);

  k_final<<<BATCH, 512, 0, stream>>>(P3, FW, ULAST, W1, b1, W2, b2, out);
}

// Round 15
// 419.748 us; speedup vs baseline: 1.4204x; 1.1939x over previous
//
#include <hip/hip_runtime.h>
#include <hip/hip_bf16.h>
#include <stdint.h>

// ResRnn via first-order expansion in eps (method err ~1e-3 << 2.62):
//   tables: pi^t / pi^-t via composition doubling
//   stage1: permuted prefix sum -> U (fp8 e4m3) + ULAST (fp32)
//   k_mlp : FUSED F = relu(U@W1^T+b1)@W2^T + b2
//           phase 1 fp8 (U,W1; corrected 2-way swizzle), phase 2 bf16 (Hs,W2)
//   stage3: e-reduction register gather (F bf16)
//   final : exact fp32 last step (+ fused s3b).

#define T_STEPS 2048
#define BATCH 64
#define IN_W 256
#define SW 512
#define EPS 1e-5f
#define NCHUNK 64
#define CLEN 32
#define QSTEP 32
#define NQ 65

typedef __bf16 bf16x8 __attribute__((ext_vector_type(8)));
typedef float f32x4 __attribute__((ext_vector_type(4)));

__device__ __forceinline__ unsigned short bf16bits(float v) {
  __hip_bfloat16 h = __float2bfloat16(v);
  return *reinterpret_cast<unsigned short*>(&h);
}

__device__ __forceinline__ float bf16val(unsigned short u) {
  unsigned int x = ((unsigned int)u) << 16;
  return __uint_as_float(x);
}

// float -> OCP e4m3 (RNE, clamp +-448, flush |x|<2^-6 to 0; no denormals)
__device__ __forceinline__ unsigned char f32_to_e4m3(float f) {
  unsigned char sign = (__float_as_uint(f) >> 24) & 0x80u;
  float a = fabsf(f);
  if (a < 0.015625f) return sign;
  if (a > 448.f) a = 448.f;
  int e;
  (void)frexpf(a, &e);                         // a = m*2^e, m in [.5,1)
  float q = ldexpf(rintf(ldexpf(a, 4 - e)), e - 4);  // ulp = 2^(e-4)
  unsigned int qu = __float_as_uint(q);
  int qe = (int)((qu >> 23) & 0xFF) - 127;
  unsigned int qm = (qu >> 20) & 0x7;
  return sign | (unsigned char)(((qe + 7) << 3) | qm);
}

__device__ __forceinline__ void gload_lds16(const void* g, const void* l) {
  __builtin_amdgcn_global_load_lds(
      (const __attribute__((address_space(1))) unsigned int*)(uintptr_t)g,
      (__attribute__((address_space(3))) unsigned int*)(uintptr_t)l, 16, 0, 0);
}

// ---------------- permutation power tables (doubling) ------------------------
__global__ __launch_bounds__(512) void k_tabA(const int* __restrict__ perm,
                                              int* __restrict__ FW, int* __restrict__ IDXI) {
  __shared__ int pl[SW], il[SW];
  int j = threadIdx.x;
  pl[j] = perm[j];
  __syncthreads();
  il[pl[j]] = j;
  __syncthreads();
  int f = j, iv = j;
  FW[j] = f; IDXI[j] = iv;
  for (int t = 1; t <= QSTEP; ++t) {
    f = pl[f]; iv = il[iv];
    FW[t * SW + j] = f; IDXI[t * SW + j] = iv;
  }
}

__global__ __launch_bounds__(512) void k_tabB(const int* __restrict__ FW, const int* __restrict__ IDXI,
                                              int* __restrict__ FWQ, int* __restrict__ IDXIQ) {
  __shared__ int f32r[SW], i32r[SW];
  int j = threadIdx.x;
  f32r[j] = FW[QSTEP * SW + j];
  i32r[j] = IDXI[QSTEP * SW + j];
  __syncthreads();
  int f = j, iv = j;
  FWQ[j] = f; IDXIQ[j] = iv;
  for (int q = 1; q < NQ; ++q) {
    f = f32r[f]; iv = i32r[iv];
    FWQ[q * SW + j] = f; IDXIQ[q * SW + j] = iv;
  }
}

__global__ __launch_bounds__(512) void k_tabC(const int* __restrict__ FWQ, const int* __restrict__ IDXIQ,
                                              int* __restrict__ FW, int* __restrict__ IDXI) {
  int t = blockIdx.x;
  if (t <= QSTEP) return;
  int j = threadIdx.x;
  int q = t >> 5, r = t & 31;
  int a = FW[r * SW + j];
  FW[(size_t)t * SW + j] = FWQ[q * SW + a];
  int b = IDXI[r * SW + j];
  IDXI[(size_t)t * SW + j] = IDXIQ[q * SW + b];
}

// ---------------- weights: W1 -> fp8, W2 -> bf16 -----------------------------
__global__ __launch_bounds__(256) void k_wcast(const float* __restrict__ W1,
                                               const float* __restrict__ W2,
                                               unsigned char* __restrict__ W1q,
                                               __hip_bfloat16* __restrict__ W2b) {
  int i = blockIdx.x * 256 + threadIdx.x;
  if (i < SW * SW) W1q[i] = f32_to_e4m3(W1[i]);
  else W2b[i - SW * SW] = __float2bfloat16(W2[i - SW * SW]);
}

// ---------------- stage 1a: chunk sums, 8-deep staged register gather --------
__global__ __launch_bounds__(512) void k_s1a(const float* __restrict__ x,
                                             const int* __restrict__ IDXI,
                                             float* __restrict__ P1) {
  __shared__ float xs[8][IN_W] __attribute__((aligned(16)));
  int c = blockIdx.x, b = blockIdx.y, tid = threadIdx.x;
  const int r = tid >> 6;
  const int colx = (tid & 63) * 4;
  float acc = 0.f;
  int t0 = c * CLEN;
  for (int tt = 0; tt < CLEN; tt += 8) {
    *reinterpret_cast<f32x4*>(&xs[r][colx]) =
        *reinterpret_cast<const f32x4*>(&x[((size_t)(t0 + tt + r) * BATCH + b) * IN_W + colx]);
    __syncthreads();
#pragma unroll
    for (int k = 0; k < 8; ++k) {
      int i0 = IDXI[(size_t)(t0 + tt + k) * SW + tid];
      if (i0 < IN_W) acc += xs[k][i0];
    }
    __syncthreads();
  }
  P1[((size_t)c * BATCH + b) * SW + tid] = acc;
}

__global__ __launch_bounds__(512) void k_s1b(const float* __restrict__ init,
                                             float* __restrict__ P1) {
  int b = blockIdx.x, i = threadIdx.x;
  float run = EPS * init[i];
  for (int c = 0; c < NCHUNK; ++c) {
    size_t o = ((size_t)c * BATCH + b) * SW + i;
    float t = P1[o]; P1[o] = run; run += t;
  }
}

// ---------------- stage 1c: prefix walk -> fp8 U + fp32 ULAST ----------------
__global__ __launch_bounds__(512) void k_s1c(const float* __restrict__ x,
                                             const int* __restrict__ IDXI,
                                             const float* __restrict__ P1,
                                             unsigned char* __restrict__ U,
                                             float* __restrict__ ULAST) {
  __shared__ float xs[8][IN_W] __attribute__((aligned(16)));
  __shared__ unsigned char us[8][SW] __attribute__((aligned(16)));
  __shared__ float ul[SW] __attribute__((aligned(16)));
  int c = blockIdx.x, b = blockIdx.y, tid = threadIdx.x;
  float v = P1[((size_t)c * BATCH + b) * SW + tid];
  int t0 = c * CLEN;
  const int r = tid >> 6;
  const int colx = (tid & 63) * 4;
  for (int tt = 0; tt < CLEN; tt += 8) {
    *reinterpret_cast<f32x4*>(&xs[r][colx]) =
        *reinterpret_cast<const f32x4*>(&x[((size_t)(t0 + tt + r) * BATCH + b) * IN_W + colx]);
    __syncthreads();
#pragma unroll
    for (int k = 0; k < 8; ++k) {
      int t = t0 + tt + k;
      int i0 = IDXI[(size_t)t * SW + tid];
      int i1 = IDXI[(size_t)(t + 1) * SW + tid];
      if (i0 < IN_W) v += xs[k][i0];
      us[k][i1] = f32_to_e4m3(v);
      if (t == T_STEPS - 1) ul[i1] = v;
    }
    __syncthreads();
    if (tid < 256) {   // 8 rows x 32 granules of 16B
      int row = tid >> 5, g = tid & 31;
      *reinterpret_cast<int4*>(U + ((size_t)(t0 + tt + row) * BATCH + b) * SW + g * 16) =
          *reinterpret_cast<const int4*>(&us[row][g * 16]);
    }
    __syncthreads();
  }
  if (c == NCHUNK - 1) ULAST[(size_t)b * SW + tid] = ul[tid];
}

// ---------------- FUSED MLP: phase-1 fp8, phase-2 bf16 -----------------------
// 512 thr (8 waves), M-slab 128. LDS 80KB (bytes):
//   phase 1: A bufs x3 fp8 [0,24K) | W1 bufs x3 fp8 [24K,48K)   (depth-3)
//   phase 2: W2 bufs x3 bf16 (16K ea, 128x64) [0,48K) | Hs bf16 [48K,80K)
//   epilogue scratch [0,64K)
// fp8 swizzle: 16B source granule sg = pg ^ ((row>>2)&3)  (2-way on b64 reads)
__global__ __launch_bounds__(512, 2) void k_mlp(const unsigned char* __restrict__ A,
                                                const unsigned char* __restrict__ W1,
                                                const __hip_bfloat16* __restrict__ W2,
                                                const float* __restrict__ b1,
                                                const float* __restrict__ b2,
                                                __hip_bfloat16* __restrict__ Fout) {
  __shared__ unsigned char smem[81920] __attribute__((aligned(16)));
  const int tid = threadIdx.x;
  const int lane = tid & 63;
  const int wv = tid >> 6;
  const int hwr = wv >> 1, hwc = wv & 1;   // phase-1 grid 4x2 (32x64 tiles)
  const int fwr = wv >> 2, fwc = wv & 3;   // phase-2 grid 2x4 (64x32 tiles)
  const size_t m0 = (size_t)blockIdx.x * 128;
  unsigned short* Hs = reinterpret_cast<unsigned short*>(smem + 49152);

  f32x4 Facc[4][4][2];                     // [n-quarter][m][n]
#pragma unroll
  for (int q = 0; q < 4; ++q)
#pragma unroll
    for (int m = 0; m < 4; ++m)
#pragma unroll
      for (int n = 0; n < 2; ++n) Facc[q][m][n] = (f32x4)0.f;

  for (int hb = 0; hb < 4; ++hb) {
    f32x4 Hacc[2][4];
#pragma unroll
    for (int m = 0; m < 2; ++m)
#pragma unroll
      for (int n = 0; n < 4; ++n) Hacc[m][n] = (f32x4)0.f;

    // ---- phase 1 (fp8): depth-3 pipeline, 2 loads/thread/stage ----
    auto stage1 = [&](int kt, int buf) {
      int row = tid >> 2, pg = tid & 3;
      int sg = pg ^ ((row >> 2) & 3);
      gload_lds16(A + (m0 + row) * 512 + kt * 64 + sg * 16,
                  (const char*)smem + buf * 8192 + tid * 16);
      gload_lds16(W1 + (size_t)(hb * 128 + row) * 512 + kt * 64 + sg * 16,
                  (const char*)smem + 24576 + buf * 8192 + tid * 16);
    };
    stage1(0, 0);
    stage1(1, 1);
#pragma unroll
    for (int kt = 0; kt < 8; ++kt) {
      if (kt < 7) asm volatile("s_waitcnt vmcnt(2)" ::: "memory");
      else        asm volatile("s_waitcnt vmcnt(0)" ::: "memory");
      __builtin_amdgcn_s_barrier();
      if (kt < 6) stage1(kt + 2, (kt + 2) % 3);
      const unsigned char* Ab = smem + (kt % 3) * 8192;
      const unsigned char* W1b_ = smem + 24576 + (kt % 3) * 8192;
#pragma unroll
      for (int kh = 0; kh < 2; ++kh) {
        long af[2], bfw[4];
        int g = kh * 4 + (lane >> 4);
#pragma unroll
        for (int m = 0; m < 2; ++m) {
          int row = hwr * 32 + m * 16 + (lane & 15);
          int off = row * 64 + ((((g >> 1) ^ ((row >> 2) & 3)) << 4) | ((g & 1) << 3));
          af[m] = *reinterpret_cast<const long*>(Ab + off);
        }
#pragma unroll
        for (int n = 0; n < 4; ++n) {
          int row = hwc * 64 + n * 16 + (lane & 15);
          int off = row * 64 + ((((g >> 1) ^ ((row >> 2) & 3)) << 4) | ((g & 1) << 3));
          bfw[n] = *reinterpret_cast<const long*>(W1b_ + off);
        }
#pragma unroll
        for (int m = 0; m < 2; ++m)
#pragma unroll
          for (int n = 0; n < 4; ++n)
            Hacc[m][n] = __builtin_amdgcn_mfma_f32_16x16x32_fp8_fp8(af[m], bfw[n], Hacc[m][n], 0, 0, 0);
      }
    }
    __syncthreads();  // all phase-1 LDS reads done

    // issue W2 round-0 (128 N-rows x 64 k bf16 = 16KB) into W2 buf 0 [0,16K)
    {
#pragma unroll
      for (int s = 0; s < 2; ++s) {
        int idx = s * 512 + tid;          // 1024 granules (128 rows x 8 of 16B)
        int row = idx >> 3, pg = idx & 7;
        int sg = pg ^ (row & 7);
        gload_lds16(W2 + (size_t)row * 512 + hb * 128 + sg * 8,
                    (const char*)smem + idx * 16);
      }
    }

    // Hacc + b1 -> relu -> bf16 Hs [128 rows][16 granules], phys = hg^(row&15)
    {
      const int rl = (lane >> 4) * 4;
      const int cl = lane & 15;
#pragma unroll
      for (int m = 0; m < 2; ++m)
#pragma unroll
        for (int n = 0; n < 4; ++n) {
          int coll = hwc * 64 + n * 16 + cl;
          float bv = b1[hb * 128 + coll];
#pragma unroll
          for (int r = 0; r < 4; ++r) {
            int rowl = hwr * 32 + m * 16 + rl + r;
            float h = Hacc[m][n][r] + bv;
            h = h > 0.f ? h : 0.f;
            int phys = (coll >> 3) ^ (rowl & 15);
            Hs[rowl * 128 + phys * 8 + (coll & 7)] = bf16bits(h);
          }
        }
    }
    __syncthreads();  // drains W2 round-0 + Hs writes

    // ---- phase 2 (bf16): 8 rounds r=(nh2=r>>1, ks=r&1), W2 tri-buffer ----
#pragma unroll
    for (int r = 0; r < 8; ++r) {
      if (r < 7) {
        int rn = r + 1;
        int nh2n = rn >> 1, ksn = rn & 1;
        int regbyte = (rn % 3) * 16384;
#pragma unroll
        for (int s = 0; s < 2; ++s) {
          int idx = s * 512 + tid;
          int row = idx >> 3, pg = idx & 7;
          int sg = pg ^ (row & 7);
          gload_lds16(W2 + (size_t)(nh2n * 128 + row) * 512 + hb * 128 + ksn * 64 + sg * 8,
                      (const char*)smem + regbyte + idx * 16);
        }
      }
      if (r > 0) {
        if (r < 7) asm volatile("s_waitcnt vmcnt(2)" ::: "memory");
        else       asm volatile("s_waitcnt vmcnt(0)" ::: "memory");
        __builtin_amdgcn_s_barrier();
      }
      const int nh2 = r >> 1, ks = r & 1;
      const unsigned short* w2b =
          reinterpret_cast<const unsigned short*>(smem + (r % 3) * 16384);
#pragma unroll
      for (int kh = 0; kh < 2; ++kh) {
        bf16x8 afH[4], bf2[2];
#pragma unroll
        for (int m = 0; m < 4; ++m) {
          int row = fwr * 64 + m * 16 + (lane & 15);
          int hg = ks * 8 + kh * 4 + (lane >> 4);
          int phys = hg ^ (row & 15);
          afH[m] = *reinterpret_cast<const bf16x8*>(&Hs[row * 128 + phys * 8]);
        }
#pragma unroll
        for (int n = 0; n < 2; ++n) {
          int row = fwc * 32 + n * 16 + (lane & 15);   // N within 128-quarter
          int lg = kh * 4 + (lane >> 4);
          int phys = lg ^ (row & 7);
          bf2[n] = *reinterpret_cast<const bf16x8*>(&w2b[row * 64 + phys * 8]);
        }
#pragma unroll
        for (int m = 0; m < 4; ++m)
#pragma unroll
          for (int n = 0; n < 2; ++n)
            Facc[nh2][m][n] = __builtin_amdgcn_mfma_f32_16x16x32_bf16(afH[m], bf2[n], Facc[nh2][m][n], 0, 0, 0);
      }
    }
    __syncthreads();  // phase-2 LDS reads done before next hb / epilogue
  }

  // ---- F epilogue: Facc + b2 -> scratch [128][256] bf16 -> int4 stores ------
  unsigned short* sm16 = reinterpret_cast<unsigned short*>(smem);
  const int rl = (lane >> 4) * 4;
  const int cl = lane & 15;
#pragma unroll
  for (int p = 0; p < 2; ++p) {      // col halves: quarters {2p, 2p+1}
#pragma unroll
    for (int qh = 0; qh < 2; ++qh) {
      int q = 2 * p + qh;
#pragma unroll
      for (int m = 0; m < 4; ++m)
#pragma unroll
        for (int n = 0; n < 2; ++n) {
          int coll = qh * 128 + fwc * 32 + n * 16 + cl;   // within 256
          float bv = b2[p * 256 + coll];
#pragma unroll
          for (int r = 0; r < 4; ++r) {
            int rowl = fwr * 64 + m * 16 + rl + r;
            float v = Facc[q][m][n][r] + bv;
            int phys = (coll >> 3) ^ (rowl & 31);
            sm16[rowl * 256 + phys * 8 + (coll & 7)] = bf16bits(v);
          }
        }
    }
    __syncthreads();
#pragma unroll
    for (int s = 0; s < 8; ++s) {
      int idx = s * 512 + tid;
      int rowl = idx >> 5, g = idx & 31;
      int phys = g ^ (rowl & 31);
      *reinterpret_cast<int4*>(Fout + (m0 + rowl) * 512 + p * 256 + g * 8) =
          *reinterpret_cast<const int4*>(&sm16[rowl * 256 + phys * 8]);
    }
    __syncthreads();
  }
}

// ---------------- stage 3a: 8-deep staged register gather (bf16 F) -----------
__global__ __launch_bounds__(512) void k_s3a(const __hip_bfloat16* __restrict__ F,
                                             const int* __restrict__ IDXI,
                                             float* __restrict__ P3) {
  __shared__ unsigned short fs[8][SW] __attribute__((aligned(16)));
  int c = blockIdx.x, b = blockIdx.y, tid = threadIdx.x;
  const int r = tid >> 6;
  const int colf = (tid & 63) * 8;
  float acc = 0.f;
  int t0 = c * CLEN;
  for (int tt = 0; tt < CLEN; tt += 8) {
    *reinterpret_cast<int4*>(&fs[r][colf]) =
        *reinterpret_cast<const int4*>(&F[((size_t)(t0 + tt + r) * BATCH + b) * SW + colf]);
    __syncthreads();
#pragma unroll
    for (int k = 0; k < 8; ++k) {
      int t = t0 + tt + k;
      if (t < T_STEPS - 1) {
        int i0 = IDXI[(size_t)t * SW + tid];
        acc += bf16val(fs[k][i0]);
      }
    }
    __syncthreads();
  }
  P3[((size_t)c * BATCH + b) * SW + tid] = acc;
}

// ---------------- exact fp32 final step (+ fused s3b) ------------------------
__global__ __launch_bounds__(512) void k_final(const float* __restrict__ P3,
                                               const int* __restrict__ FW,
                                               const float* __restrict__ ULAST,
                                               const float* __restrict__ W1,
                                               const float* __restrict__ b1,
                                               const float* __restrict__ W2,
                                               const float* __restrict__ b2,
                                               float* __restrict__ out) {
  __shared__ float ml[SW] __attribute__((aligned(16)));
  __shared__ float uc[SW] __attribute__((aligned(16)));
  __shared__ float hh[SW] __attribute__((aligned(16)));
  int b = blockIdx.x, j = threadIdx.x;
  float s = 0.f;
  for (int c = 0; c < NCHUNK; ++c) s += P3[((size_t)c * BATCH + b) * SW + j];
  ml[j] = s;
  __syncthreads();
  float e = ml[FW[(size_t)(T_STEPS - 1) * SW + j]];
  float u = ULAST[(size_t)b * SW + j] + EPS * e;
  uc[j] = u;
  __syncthreads();
  float pre = b1[j];
  {
    const f32x4* wr = (const f32x4*)(W1 + (size_t)j * SW);
    const f32x4* uv = (const f32x4*)uc;
    for (int k = 0; k < SW / 4; ++k) {
      f32x4 wv = wr[k], vv = uv[k];
      pre += wv[0] * vv[0] + wv[1] * vv[1] + wv[2] * vv[2] + wv[3] * vv[3];
    }
  }
  hh[j] = pre > 0.f ? pre : 0.f;
  __syncthreads();
  float d = b2[j];
  {
    const f32x4* wr = (const f32x4*)(W2 + (size_t)j * SW);
    const f32x4* hv = (const f32x4*)hh;
    for (int k = 0; k < SW / 4; ++k) {
      f32x4 wv = wr[k], vv = hv[k];
      d += wv[0] * vv[0] + wv[1] * vv[1] + wv[2] * vv[2] + wv[3] * vv[3];
    }
  }
  float sT = u + EPS * d;
  out[BATCH * 128 + (size_t)b * SW + j] = sT;                // last  [64,512]
  if (j >= SW - 128) out[b * 128 + (j - (SW - 128))] = sT;   // outputs [64,128]
}

// ---------------- host -------------------------------------------------------
extern "C" void kernel_launch(void* const* d_in, const int* in_sizes, int n_in,
                              void* d_out, int out_size, void* d_ws, size_t ws_size,
                              hipStream_t stream) {
  const float* x = (const float*)d_in[0];
  const float* init = (const float*)d_in[1];
  const float* W1 = (const float*)d_in[2];
  const float* b1 = (const float*)d_in[3];
  const float* W2 = (const float*)d_in[4];
  const float* b2 = (const float*)d_in[5];
  const int* perm = (const int*)d_in[6];
  float* out = (float*)d_out;

  char* w = (char*)d_ws;
  size_t off = 0;
  auto alloc = [&](size_t bytes) {
    size_t o = off;
    off = (off + bytes + 255) & ~(size_t)255;
    return o;
  };
  size_t oFW   = alloc((size_t)(T_STEPS + 1) * SW * 4);
  size_t oIDXI = alloc((size_t)(T_STEPS + 1) * SW * 4);
  size_t oFWQ  = alloc((size_t)NQ * SW * 4);
  size_t oIDXQ = alloc((size_t)NQ * SW * 4);
  size_t oW1q  = alloc((size_t)SW * SW);
  size_t oW2b  = alloc((size_t)SW * SW * 2);
  size_t oU    = alloc((size_t)T_STEPS * BATCH * SW);      // fp8
  size_t oF    = alloc((size_t)T_STEPS * BATCH * SW * 2);  // bf16
  size_t oP1   = alloc((size_t)NCHUNK * BATCH * SW * 4);
  size_t oP3   = alloc((size_t)NCHUNK * BATCH * SW * 4);
  size_t oUL   = alloc((size_t)BATCH * SW * 4);
  if (off > ws_size) return;

  int* FW = (int*)(w + oFW);
  int* IDXI = (int*)(w + oIDXI);
  int* FWQ = (int*)(w + oFWQ);
  int* IDXIQ = (int*)(w + oIDXQ);
  unsigned char* W1q = (unsigned char*)(w + oW1q);
  __hip_bfloat16* W2b = (__hip_bfloat16*)(w + oW2b);
  unsigned char* U = (unsigned char*)(w + oU);
  __hip_bfloat16* F = (__hip_bfloat16*)(w + oF);
  float* P1 = (float*)(w + oP1);
  float* P3 = (float*)(w + oP3);
  float* ULAST = (float*)(w + oUL);

  k_tabA<<<1, 512, 0, stream>>>(perm, FW, IDXI);
  k_tabB<<<1, 512, 0, stream>>>(FW, IDXI, FWQ, IDXIQ);
  k_tabC<<<T_STEPS + 1, 512, 0, stream>>>(FWQ, IDXIQ, FW, IDXI);
  k_wcast<<<(2 * SW * SW + 255) / 256, 256, 0, stream>>>(W1, W2, W1q, W2b);

  k_s1a<<<dim3(NCHUNK, BATCH), 512, 0, stream>>>(x, IDXI, P1);
  k_s1b<<<BATCH, 512, 0, stream>>>(init, P1);
  k_s1c<<<dim3(NCHUNK, BATCH), 512, 0, stream>>>(x, IDXI, P1, U, ULAST);

  k_mlp<<<(T_STEPS * BATCH) / 128, 512, 0, stream>>>(U, W1q, W2b, b1, b2, F);

  k_s3a<<<dim3(NCHUNK, BATCH), 512, 0, stream>>>(F, IDXI, P3);

  k_final<<<BATCH, 512, 0, stream>>>(P3, FW, ULAST, W1, b1, W2, b2, out);
}

// Round 16
// 403.652 us; speedup vs baseline: 1.4771x; 1.0399x over previous
//
#include <hip/hip_runtime.h>
#include <hip/hip_bf16.h>
#include <stdint.h>

// ResRnn via first-order expansion in eps (method err ~1e-3 << 2.62):
//   tables: pi^t / pi^-t via composition doubling
//   stage1: permuted prefix sum -> U (fp8 e4m3, HW cvt) + ULAST (fp32)
//   k_mlp : FUSED F = relu(U@W1^T+b1)@W2^T + b2  [r15 frozen:
//           phase 1 fp8 (2-way swizzle), phase 2 bf16, depth-3 vmcnt pipes]
//   stage3: e-reduction register gather (F bf16), 16-deep staging
//   final : exact fp32 last step (+ fused s3b).

#define T_STEPS 2048
#define BATCH 64
#define IN_W 256
#define SW 512
#define EPS 1e-5f
#define NCHUNK 64
#define CLEN 32
#define QSTEP 32
#define NQ 65

typedef __bf16 bf16x8 __attribute__((ext_vector_type(8)));
typedef float f32x4 __attribute__((ext_vector_type(4)));

__device__ __forceinline__ unsigned short bf16bits(float v) {
  __hip_bfloat16 h = __float2bfloat16(v);
  return *reinterpret_cast<unsigned short*>(&h);
}

__device__ __forceinline__ float bf16val(unsigned short u) {
  unsigned int x = ((unsigned int)u) << 16;
  return __uint_as_float(x);
}

// float -> OCP e4m3 via HW v_cvt_pk_fp8_f32 (RNE, saturating)
__device__ __forceinline__ unsigned char f8cvt(float v) {
  return (unsigned char)(__builtin_amdgcn_cvt_pk_fp8_f32(v, v, 0, false) & 0xff);
}

__device__ __forceinline__ void gload_lds16(const void* g, const void* l) {
  __builtin_amdgcn_global_load_lds(
      (const __attribute__((address_space(1))) unsigned int*)(uintptr_t)g,
      (__attribute__((address_space(3))) unsigned int*)(uintptr_t)l, 16, 0, 0);
}

// ---------------- permutation power tables (doubling) ------------------------
__global__ __launch_bounds__(512) void k_tabA(const int* __restrict__ perm,
                                              int* __restrict__ FW, int* __restrict__ IDXI) {
  __shared__ int pl[SW], il[SW];
  int j = threadIdx.x;
  pl[j] = perm[j];
  __syncthreads();
  il[pl[j]] = j;
  __syncthreads();
  int f = j, iv = j;
  FW[j] = f; IDXI[j] = iv;
  for (int t = 1; t <= QSTEP; ++t) {
    f = pl[f]; iv = il[iv];
    FW[t * SW + j] = f; IDXI[t * SW + j] = iv;
  }
}

__global__ __launch_bounds__(512) void k_tabB(const int* __restrict__ FW, const int* __restrict__ IDXI,
                                              int* __restrict__ FWQ, int* __restrict__ IDXIQ) {
  __shared__ int f32r[SW], i32r[SW];
  int j = threadIdx.x;
  f32r[j] = FW[QSTEP * SW + j];
  i32r[j] = IDXI[QSTEP * SW + j];
  __syncthreads();
  int f = j, iv = j;
  FWQ[j] = f; IDXIQ[j] = iv;
  for (int q = 1; q < NQ; ++q) {
    f = f32r[f]; iv = i32r[iv];
    FWQ[q * SW + j] = f; IDXIQ[q * SW + j] = iv;
  }
}

__global__ __launch_bounds__(512) void k_tabC(const int* __restrict__ FWQ, const int* __restrict__ IDXIQ,
                                              int* __restrict__ FW, int* __restrict__ IDXI) {
  int t = blockIdx.x;
  if (t <= QSTEP) return;
  int j = threadIdx.x;
  int q = t >> 5, r = t & 31;
  int a = FW[r * SW + j];
  FW[(size_t)t * SW + j] = FWQ[q * SW + a];
  int b = IDXI[r * SW + j];
  IDXI[(size_t)t * SW + j] = IDXIQ[q * SW + b];
}

// ---------------- weights: W1 -> fp8 (HW cvt), W2 -> bf16 --------------------
__global__ __launch_bounds__(256) void k_wcast(const float* __restrict__ W1,
                                               const float* __restrict__ W2,
                                               unsigned char* __restrict__ W1q,
                                               __hip_bfloat16* __restrict__ W2b) {
  int i = blockIdx.x * 256 + threadIdx.x;
  if (i < SW * SW) W1q[i] = f8cvt(W1[i]);
  else W2b[i - SW * SW] = __float2bfloat16(W2[i - SW * SW]);
}

// ---------------- stage 1a: chunk sums, 16-deep staged register gather -------
__global__ __launch_bounds__(512) void k_s1a(const float* __restrict__ x,
                                             const int* __restrict__ IDXI,
                                             float* __restrict__ P1) {
  __shared__ float xs[16][IN_W] __attribute__((aligned(16)));
  int c = blockIdx.x, b = blockIdx.y, tid = threadIdx.x;
  float acc = 0.f;
  int t0 = c * CLEN;
  for (int tt = 0; tt < CLEN; tt += 16) {
#pragma unroll
    for (int s = 0; s < 2; ++s) {
      int idx = s * 512 + tid;
      int row = idx >> 6, col = (idx & 63) * 4;
      *reinterpret_cast<f32x4*>(&xs[row][col]) =
          *reinterpret_cast<const f32x4*>(&x[((size_t)(t0 + tt + row) * BATCH + b) * IN_W + col]);
    }
    __syncthreads();
#pragma unroll
    for (int k = 0; k < 16; ++k) {
      int i0 = IDXI[(size_t)(t0 + tt + k) * SW + tid];
      if (i0 < IN_W) acc += xs[k][i0];
    }
    __syncthreads();
  }
  P1[((size_t)c * BATCH + b) * SW + tid] = acc;
}

// ---------------- stage 1b: chunk scan, 16-deep batched loads ----------------
__global__ __launch_bounds__(512) void k_s1b(const float* __restrict__ init,
                                             float* __restrict__ P1) {
  int b = blockIdx.x, i = threadIdx.x;
  float run = EPS * init[i];
  float v[16];
  for (int g = 0; g < NCHUNK / 16; ++g) {
#pragma unroll
    for (int k = 0; k < 16; ++k)
      v[k] = P1[((size_t)(g * 16 + k) * BATCH + b) * SW + i];
#pragma unroll
    for (int k = 0; k < 16; ++k) {
      P1[((size_t)(g * 16 + k) * BATCH + b) * SW + i] = run;
      run += v[k];
    }
  }
}

// ---------------- stage 1c: prefix walk -> fp8 U + fp32 ULAST ----------------
// 16-deep staging, carried index (i1(t) == i0(t+1)), HW fp8 cvt.
__global__ __launch_bounds__(512) void k_s1c(const float* __restrict__ x,
                                             const int* __restrict__ IDXI,
                                             const float* __restrict__ P1,
                                             unsigned char* __restrict__ U,
                                             float* __restrict__ ULAST) {
  __shared__ float xs[16][IN_W] __attribute__((aligned(16)));
  __shared__ unsigned char us[16][SW] __attribute__((aligned(16)));
  __shared__ float ul[SW] __attribute__((aligned(16)));
  int c = blockIdx.x, b = blockIdx.y, tid = threadIdx.x;
  float v = P1[((size_t)c * BATCH + b) * SW + tid];
  int t0 = c * CLEN;
  int cur = IDXI[(size_t)t0 * SW + tid];
  for (int tt = 0; tt < CLEN; tt += 16) {
#pragma unroll
    for (int s = 0; s < 2; ++s) {
      int idx = s * 512 + tid;
      int row = idx >> 6, col = (idx & 63) * 4;
      *reinterpret_cast<f32x4*>(&xs[row][col]) =
          *reinterpret_cast<const f32x4*>(&x[((size_t)(t0 + tt + row) * BATCH + b) * IN_W + col]);
    }
    __syncthreads();
#pragma unroll
    for (int k = 0; k < 16; ++k) {
      int t = t0 + tt + k;
      int nxt = IDXI[(size_t)(t + 1) * SW + tid];
      if (cur < IN_W) v += xs[k][cur];
      us[k][nxt] = f8cvt(v);
      if (t == T_STEPS - 1) ul[nxt] = v;
      cur = nxt;
    }
    __syncthreads();
    {  // dump 16 rows x 512 fp8 = 512 int4, 1 per thread
      int row = tid >> 5, g = tid & 31;
      *reinterpret_cast<int4*>(U + ((size_t)(t0 + tt + row) * BATCH + b) * SW + g * 16) =
          *reinterpret_cast<const int4*>(&us[row][g * 16]);
    }
    __syncthreads();
  }
  if (c == NCHUNK - 1) ULAST[(size_t)b * SW + tid] = ul[tid];
}

// ---------------- FUSED MLP (round-15 verbatim, frozen) ----------------------
__global__ __launch_bounds__(512, 2) void k_mlp(const unsigned char* __restrict__ A,
                                                const unsigned char* __restrict__ W1,
                                                const __hip_bfloat16* __restrict__ W2,
                                                const float* __restrict__ b1,
                                                const float* __restrict__ b2,
                                                __hip_bfloat16* __restrict__ Fout) {
  __shared__ unsigned char smem[81920] __attribute__((aligned(16)));
  const int tid = threadIdx.x;
  const int lane = tid & 63;
  const int wv = tid >> 6;
  const int hwr = wv >> 1, hwc = wv & 1;   // phase-1 grid 4x2 (32x64 tiles)
  const int fwr = wv >> 2, fwc = wv & 3;   // phase-2 grid 2x4 (64x32 tiles)
  const size_t m0 = (size_t)blockIdx.x * 128;
  unsigned short* Hs = reinterpret_cast<unsigned short*>(smem + 49152);

  f32x4 Facc[4][4][2];                     // [n-quarter][m][n]
#pragma unroll
  for (int q = 0; q < 4; ++q)
#pragma unroll
    for (int m = 0; m < 4; ++m)
#pragma unroll
      for (int n = 0; n < 2; ++n) Facc[q][m][n] = (f32x4)0.f;

  for (int hb = 0; hb < 4; ++hb) {
    f32x4 Hacc[2][4];
#pragma unroll
    for (int m = 0; m < 2; ++m)
#pragma unroll
      for (int n = 0; n < 4; ++n) Hacc[m][n] = (f32x4)0.f;

    // ---- phase 1 (fp8): depth-3 pipeline, 2 loads/thread/stage ----
    auto stage1 = [&](int kt, int buf) {
      int row = tid >> 2, pg = tid & 3;
      int sg = pg ^ ((row >> 2) & 3);
      gload_lds16(A + (m0 + row) * 512 + kt * 64 + sg * 16,
                  (const char*)smem + buf * 8192 + tid * 16);
      gload_lds16(W1 + (size_t)(hb * 128 + row) * 512 + kt * 64 + sg * 16,
                  (const char*)smem + 24576 + buf * 8192 + tid * 16);
    };
    stage1(0, 0);
    stage1(1, 1);
#pragma unroll
    for (int kt = 0; kt < 8; ++kt) {
      if (kt < 7) asm volatile("s_waitcnt vmcnt(2)" ::: "memory");
      else        asm volatile("s_waitcnt vmcnt(0)" ::: "memory");
      __builtin_amdgcn_s_barrier();
      if (kt < 6) stage1(kt + 2, (kt + 2) % 3);
      const unsigned char* Ab = smem + (kt % 3) * 8192;
      const unsigned char* W1b_ = smem + 24576 + (kt % 3) * 8192;
#pragma unroll
      for (int kh = 0; kh < 2; ++kh) {
        long af[2], bfw[4];
        int g = kh * 4 + (lane >> 4);
#pragma unroll
        for (int m = 0; m < 2; ++m) {
          int row = hwr * 32 + m * 16 + (lane & 15);
          int off = row * 64 + ((((g >> 1) ^ ((row >> 2) & 3)) << 4) | ((g & 1) << 3));
          af[m] = *reinterpret_cast<const long*>(Ab + off);
        }
#pragma unroll
        for (int n = 0; n < 4; ++n) {
          int row = hwc * 64 + n * 16 + (lane & 15);
          int off = row * 64 + ((((g >> 1) ^ ((row >> 2) & 3)) << 4) | ((g & 1) << 3));
          bfw[n] = *reinterpret_cast<const long*>(W1b_ + off);
        }
#pragma unroll
        for (int m = 0; m < 2; ++m)
#pragma unroll
          for (int n = 0; n < 4; ++n)
            Hacc[m][n] = __builtin_amdgcn_mfma_f32_16x16x32_fp8_fp8(af[m], bfw[n], Hacc[m][n], 0, 0, 0);
      }
    }
    __syncthreads();  // all phase-1 LDS reads done

    // issue W2 round-0 (128 N-rows x 64 k bf16 = 16KB) into W2 buf 0 [0,16K)
    {
#pragma unroll
      for (int s = 0; s < 2; ++s) {
        int idx = s * 512 + tid;          // 1024 granules (128 rows x 8 of 16B)
        int row = idx >> 3, pg = idx & 7;
        int sg = pg ^ (row & 7);
        gload_lds16(W2 + (size_t)row * 512 + hb * 128 + sg * 8,
                    (const char*)smem + idx * 16);
      }
    }

    // Hacc + b1 -> relu -> bf16 Hs [128 rows][16 granules], phys = hg^(row&15)
    {
      const int rl = (lane >> 4) * 4;
      const int cl = lane & 15;
#pragma unroll
      for (int m = 0; m < 2; ++m)
#pragma unroll
        for (int n = 0; n < 4; ++n) {
          int coll = hwc * 64 + n * 16 + cl;
          float bv = b1[hb * 128 + coll];
#pragma unroll
          for (int r = 0; r < 4; ++r) {
            int rowl = hwr * 32 + m * 16 + rl + r;
            float h = Hacc[m][n][r] + bv;
            h = h > 0.f ? h : 0.f;
            int phys = (coll >> 3) ^ (rowl & 15);
            Hs[rowl * 128 + phys * 8 + (coll & 7)] = bf16bits(h);
          }
        }
    }
    __syncthreads();  // drains W2 round-0 + Hs writes

    // ---- phase 2 (bf16): 8 rounds r=(nh2=r>>1, ks=r&1), W2 tri-buffer ----
#pragma unroll
    for (int r = 0; r < 8; ++r) {
      if (r < 7) {
        int rn = r + 1;
        int nh2n = rn >> 1, ksn = rn & 1;
        int regbyte = (rn % 3) * 16384;
#pragma unroll
        for (int s = 0; s < 2; ++s) {
          int idx = s * 512 + tid;
          int row = idx >> 3, pg = idx & 7;
          int sg = pg ^ (row & 7);
          gload_lds16(W2 + (size_t)(nh2n * 128 + row) * 512 + hb * 128 + ksn * 64 + sg * 8,
                      (const char*)smem + regbyte + idx * 16);
        }
      }
      if (r > 0) {
        if (r < 7) asm volatile("s_waitcnt vmcnt(2)" ::: "memory");
        else       asm volatile("s_waitcnt vmcnt(0)" ::: "memory");
        __builtin_amdgcn_s_barrier();
      }
      const int nh2 = r >> 1, ks = r & 1;
      const unsigned short* w2b =
          reinterpret_cast<const unsigned short*>(smem + (r % 3) * 16384);
#pragma unroll
      for (int kh = 0; kh < 2; ++kh) {
        bf16x8 afH[4], bf2[2];
#pragma unroll
        for (int m = 0; m < 4; ++m) {
          int row = fwr * 64 + m * 16 + (lane & 15);
          int hg = ks * 8 + kh * 4 + (lane >> 4);
          int phys = hg ^ (row & 15);
          afH[m] = *reinterpret_cast<const bf16x8*>(&Hs[row * 128 + phys * 8]);
        }
#pragma unroll
        for (int n = 0; n < 2; ++n) {
          int row = fwc * 32 + n * 16 + (lane & 15);   // N within 128-quarter
          int lg = kh * 4 + (lane >> 4);
          int phys = lg ^ (row & 7);
          bf2[n] = *reinterpret_cast<const bf16x8*>(&w2b[row * 64 + phys * 8]);
        }
#pragma unroll
        for (int m = 0; m < 4; ++m)
#pragma unroll
          for (int n = 0; n < 2; ++n)
            Facc[nh2][m][n] = __builtin_amdgcn_mfma_f32_16x16x32_bf16(afH[m], bf2[n], Facc[nh2][m][n], 0, 0, 0);
      }
    }
    __syncthreads();  // phase-2 LDS reads done before next hb / epilogue
  }

  // ---- F epilogue: Facc + b2 -> scratch [128][256] bf16 -> int4 stores ------
  unsigned short* sm16 = reinterpret_cast<unsigned short*>(smem);
  const int rl = (lane >> 4) * 4;
  const int cl = lane & 15;
#pragma unroll
  for (int p = 0; p < 2; ++p) {      // col halves: quarters {2p, 2p+1}
#pragma unroll
    for (int qh = 0; qh < 2; ++qh) {
      int q = 2 * p + qh;
#pragma unroll
      for (int m = 0; m < 4; ++m)
#pragma unroll
        for (int n = 0; n < 2; ++n) {
          int coll = qh * 128 + fwc * 32 + n * 16 + cl;   // within 256
          float bv = b2[p * 256 + coll];
#pragma unroll
          for (int r = 0; r < 4; ++r) {
            int rowl = fwr * 64 + m * 16 + rl + r;
            float v = Facc[q][m][n][r] + bv;
            int phys = (coll >> 3) ^ (rowl & 31);
            sm16[rowl * 256 + phys * 8 + (coll & 7)] = bf16bits(v);
          }
        }
    }
    __syncthreads();
#pragma unroll
    for (int s = 0; s < 8; ++s) {
      int idx = s * 512 + tid;
      int rowl = idx >> 5, g = idx & 31;
      int phys = g ^ (rowl & 31);
      *reinterpret_cast<int4*>(Fout + (m0 + rowl) * 512 + p * 256 + g * 8) =
          *reinterpret_cast<const int4*>(&sm16[rowl * 256 + phys * 8]);
    }
    __syncthreads();
  }
}

// ---------------- stage 3a: 16-deep staged register gather (bf16 F) ----------
__global__ __launch_bounds__(512) void k_s3a(const __hip_bfloat16* __restrict__ F,
                                             const int* __restrict__ IDXI,
                                             float* __restrict__ P3) {
  __shared__ unsigned short fs[16][SW] __attribute__((aligned(16)));
  int c = blockIdx.x, b = blockIdx.y, tid = threadIdx.x;
  float acc = 0.f;
  int t0 = c * CLEN;
  for (int tt = 0; tt < CLEN; tt += 16) {
#pragma unroll
    for (int s = 0; s < 2; ++s) {
      int idx = s * 512 + tid;
      int row = idx >> 6, g = idx & 63;
      *reinterpret_cast<int4*>(&fs[row][g * 8]) =
          *reinterpret_cast<const int4*>(&F[((size_t)(t0 + tt + row) * BATCH + b) * SW + g * 8]);
    }
    __syncthreads();
#pragma unroll
    for (int k = 0; k < 16; ++k) {
      int t = t0 + tt + k;
      if (t < T_STEPS - 1) {
        int i0 = IDXI[(size_t)t * SW + tid];
        acc += bf16val(fs[k][i0]);
      }
    }
    __syncthreads();
  }
  P3[((size_t)c * BATCH + b) * SW + tid] = acc;
}

// ---------------- exact fp32 final step (+ fused s3b) ------------------------
__global__ __launch_bounds__(512) void k_final(const float* __restrict__ P3,
                                               const int* __restrict__ FW,
                                               const float* __restrict__ ULAST,
                                               const float* __restrict__ W1,
                                               const float* __restrict__ b1,
                                               const float* __restrict__ W2,
                                               const float* __restrict__ b2,
                                               float* __restrict__ out) {
  __shared__ float ml[SW] __attribute__((aligned(16)));
  __shared__ float uc[SW] __attribute__((aligned(16)));
  __shared__ float hh[SW] __attribute__((aligned(16)));
  int b = blockIdx.x, j = threadIdx.x;
  float s = 0.f;
  for (int c = 0; c < NCHUNK; ++c) s += P3[((size_t)c * BATCH + b) * SW + j];
  ml[j] = s;
  __syncthreads();
  float e = ml[FW[(size_t)(T_STEPS - 1) * SW + j]];
  float u = ULAST[(size_t)b * SW + j] + EPS * e;
  uc[j] = u;
  __syncthreads();
  float pre = b1[j];
  {
    const f32x4* wr = (const f32x4*)(W1 + (size_t)j * SW);
    const f32x4* uv = (const f32x4*)uc;
    for (int k = 0; k < SW / 4; ++k) {
      f32x4 wv = wr[k], vv = uv[k];
      pre += wv[0] * vv[0] + wv[1] * vv[1] + wv[2] * vv[2] + wv[3] * vv[3];
    }
  }
  hh[j] = pre > 0.f ? pre : 0.f;
  __syncthreads();
  float d = b2[j];
  {
    const f32x4* wr = (const f32x4*)(W2 + (size_t)j * SW);
    const f32x4* hv = (const f32x4*)hh;
    for (int k = 0; k < SW / 4; ++k) {
      f32x4 wv = wr[k], vv = hv[k];
      d += wv[0] * vv[0] + wv[1] * vv[1] + wv[2] * vv[2] + wv[3] * vv[3];
    }
  }
  float sT = u + EPS * d;
  out[BATCH * 128 + (size_t)b * SW + j] = sT;                // last  [64,512]
  if (j >= SW - 128) out[b * 128 + (j - (SW - 128))] = sT;   // outputs [64,128]
}

// ---------------- host -------------------------------------------------------
extern "C" void kernel_launch(void* const* d_in, const int* in_sizes, int n_in,
                              void* d_out, int out_size, void* d_ws, size_t ws_size,
                              hipStream_t stream) {
  const float* x = (const float*)d_in[0];
  const float* init = (const float*)d_in[1];
  const float* W1 = (const float*)d_in[2];
  const float* b1 = (const float*)d_in[3];
  const float* W2 = (const float*)d_in[4];
  const float* b2 = (const float*)d_in[5];
  const int* perm = (const int*)d_in[6];
  float* out = (float*)d_out;

  char* w = (char*)d_ws;
  size_t off = 0;
  auto alloc = [&](size_t bytes) {
    size_t o = off;
    off = (off + bytes + 255) & ~(size_t)255;
    return o;
  };
  size_t oFW   = alloc((size_t)(T_STEPS + 1) * SW * 4);
  size_t oIDXI = alloc((size_t)(T_STEPS + 1) * SW * 4);
  size_t oFWQ  = alloc((size_t)NQ * SW * 4);
  size_t oIDXQ = alloc((size_t)NQ * SW * 4);
  size_t oW1q  = alloc((size_t)SW * SW);
  size_t oW2b  = alloc((size_t)SW * SW * 2);
  size_t oU    = alloc((size_t)T_STEPS * BATCH * SW);      // fp8
  size_t oF    = alloc((size_t)T_STEPS * BATCH * SW * 2);  // bf16
  size_t oP1   = alloc((size_t)NCHUNK * BATCH * SW * 4);
  size_t oP3   = alloc((size_t)NCHUNK * BATCH * SW * 4);
  size_t oUL   = alloc((size_t)BATCH * SW * 4);
  if (off > ws_size) return;

  int* FW = (int*)(w + oFW);
  int* IDXI = (int*)(w + oIDXI);
  int* FWQ = (int*)(w + oFWQ);
  int* IDXIQ = (int*)(w + oIDXQ);
  unsigned char* W1q = (unsigned char*)(w + oW1q);
  __hip_bfloat16* W2b = (__hip_bfloat16*)(w + oW2b);
  unsigned char* U = (unsigned char*)(w + oU);
  __hip_bfloat16* F = (__hip_bfloat16*)(w + oF);
  float* P1 = (float*)(w + oP1);
  float* P3 = (float*)(w + oP3);
  float* ULAST = (float*)(w + oUL);

  k_tabA<<<1, 512, 0, stream>>>(perm, FW, IDXI);
  k_tabB<<<1, 512, 0, stream>>>(FW, IDXI, FWQ, IDXIQ);
  k_tabC<<<T_STEPS + 1, 512, 0, stream>>>(FWQ, IDXIQ, FW, IDXI);
  k_wcast<<<(2 * SW * SW + 255) / 256, 256, 0, stream>>>(W1, W2, W1q, W2b);

  k_s1a<<<dim3(NCHUNK, BATCH), 512, 0, stream>>>(x, IDXI, P1);
  k_s1b<<<BATCH, 512, 0, stream>>>(init, P1);
  k_s1c<<<dim3(NCHUNK, BATCH), 512, 0, stream>>>(x, IDXI, P1, U, ULAST);

  k_mlp<<<(T_STEPS * BATCH) / 128, 512, 0, stream>>>(U, W1q, W2b, b1, b2, F);

  k_s3a<<<dim3(NCHUNK, BATCH), 512, 0, stream>>>(F, IDXI, P3);

  k_final<<<BATCH, 512, 0, stream>>>(P3, FW, ULAST, W1, b1, W2, b2, out);
}

// Round 17
// 371.370 us; speedup vs baseline: 1.6055x; 1.0869x over previous
//
#include <hip/hip_runtime.h>
#include <hip/hip_bf16.h>
#include <stdint.h>

// ResRnn via first-order expansion in eps (method err ~1e-3 << 2.62):
//   tables: pi^t / pi^-t via composition doubling
//   stage1: permuted prefix sum -> U (fp8 e4m3, HW cvt) + ULAST (fp32)
//   k_mlp : FUSED F = relu(U@W1^T+b1)@W2^T + b2  [phase 1 fp8, phase 2 bf16,
//           depth-3 vmcnt pipes; F now stored fp8]
//   stage3: e-reduction register gather over fp8 F, 16-deep staging
//   final : exact fp32 last step (+ fused s3b).

#define T_STEPS 2048
#define BATCH 64
#define IN_W 256
#define SW 512
#define EPS 1e-5f
#define NCHUNK 64
#define CLEN 32
#define QSTEP 32
#define NQ 65

typedef __bf16 bf16x8 __attribute__((ext_vector_type(8)));
typedef float f32x4 __attribute__((ext_vector_type(4)));

__device__ __forceinline__ unsigned short bf16bits(float v) {
  __hip_bfloat16 h = __float2bfloat16(v);
  return *reinterpret_cast<unsigned short*>(&h);
}

__device__ __forceinline__ float bf16val(unsigned short u) {
  unsigned int x = ((unsigned int)u) << 16;
  return __uint_as_float(x);
}

// float -> OCP e4m3 via HW v_cvt_pk_fp8_f32 (RNE, saturating)
__device__ __forceinline__ unsigned char f8cvt(float v) {
  return (unsigned char)(__builtin_amdgcn_cvt_pk_fp8_f32(v, v, 0, false) & 0xff);
}
// e4m3 byte -> float via HW v_cvt_f32_fp8
__device__ __forceinline__ float f8val(unsigned char u) {
  return __builtin_amdgcn_cvt_f32_fp8((int)u, 0);
}

__device__ __forceinline__ void gload_lds16(const void* g, const void* l) {
  __builtin_amdgcn_global_load_lds(
      (const __attribute__((address_space(1))) unsigned int*)(uintptr_t)g,
      (__attribute__((address_space(3))) unsigned int*)(uintptr_t)l, 16, 0, 0);
}

// ---------------- permutation power tables (doubling) ------------------------
__global__ __launch_bounds__(512) void k_tabA(const int* __restrict__ perm,
                                              int* __restrict__ FW, int* __restrict__ IDXI) {
  __shared__ int pl[SW], il[SW];
  int j = threadIdx.x;
  pl[j] = perm[j];
  __syncthreads();
  il[pl[j]] = j;
  __syncthreads();
  int f = j, iv = j;
  FW[j] = f; IDXI[j] = iv;
  for (int t = 1; t <= QSTEP; ++t) {
    f = pl[f]; iv = il[iv];
    FW[t * SW + j] = f; IDXI[t * SW + j] = iv;
  }
}

__global__ __launch_bounds__(512) void k_tabB(const int* __restrict__ FW, const int* __restrict__ IDXI,
                                              int* __restrict__ FWQ, int* __restrict__ IDXIQ) {
  __shared__ int f32r[SW], i32r[SW];
  int j = threadIdx.x;
  f32r[j] = FW[QSTEP * SW + j];
  i32r[j] = IDXI[QSTEP * SW + j];
  __syncthreads();
  int f = j, iv = j;
  FWQ[j] = f; IDXIQ[j] = iv;
  for (int q = 1; q < NQ; ++q) {
    f = f32r[f]; iv = i32r[iv];
    FWQ[q * SW + j] = f; IDXIQ[q * SW + j] = iv;
  }
}

__global__ __launch_bounds__(512) void k_tabC(const int* __restrict__ FWQ, const int* __restrict__ IDXIQ,
                                              int* __restrict__ FW, int* __restrict__ IDXI) {
  int t = blockIdx.x;
  if (t <= QSTEP) return;
  int j = threadIdx.x;
  int q = t >> 5, r = t & 31;
  int a = FW[r * SW + j];
  FW[(size_t)t * SW + j] = FWQ[q * SW + a];
  int b = IDXI[r * SW + j];
  IDXI[(size_t)t * SW + j] = IDXIQ[q * SW + b];
}

// ---------------- weights: W1 -> fp8 (HW cvt), W2 -> bf16 --------------------
__global__ __launch_bounds__(256) void k_wcast(const float* __restrict__ W1,
                                               const float* __restrict__ W2,
                                               unsigned char* __restrict__ W1q,
                                               __hip_bfloat16* __restrict__ W2b) {
  int i = blockIdx.x * 256 + threadIdx.x;
  if (i < SW * SW) W1q[i] = f8cvt(W1[i]);
  else W2b[i - SW * SW] = __float2bfloat16(W2[i - SW * SW]);
}

// ---------------- stage 1a: chunk sums, 16-deep staged register gather -------
__global__ __launch_bounds__(512) void k_s1a(const float* __restrict__ x,
                                             const int* __restrict__ IDXI,
                                             float* __restrict__ P1) {
  __shared__ float xs[16][IN_W] __attribute__((aligned(16)));
  int c = blockIdx.x, b = blockIdx.y, tid = threadIdx.x;
  float acc = 0.f;
  int t0 = c * CLEN;
  for (int tt = 0; tt < CLEN; tt += 16) {
#pragma unroll
    for (int s = 0; s < 2; ++s) {
      int idx = s * 512 + tid;
      int row = idx >> 6, col = (idx & 63) * 4;
      *reinterpret_cast<f32x4*>(&xs[row][col]) =
          *reinterpret_cast<const f32x4*>(&x[((size_t)(t0 + tt + row) * BATCH + b) * IN_W + col]);
    }
    __syncthreads();
#pragma unroll
    for (int k = 0; k < 16; ++k) {
      int i0 = IDXI[(size_t)(t0 + tt + k) * SW + tid];
      if (i0 < IN_W) acc += xs[k][i0];
    }
    __syncthreads();
  }
  P1[((size_t)c * BATCH + b) * SW + tid] = acc;
}

// ---------------- stage 1b: chunk scan, 16-deep batched loads ----------------
__global__ __launch_bounds__(512) void k_s1b(const float* __restrict__ init,
                                             float* __restrict__ P1) {
  int b = blockIdx.x, i = threadIdx.x;
  float run = EPS * init[i];
  float v[16];
  for (int g = 0; g < NCHUNK / 16; ++g) {
#pragma unroll
    for (int k = 0; k < 16; ++k)
      v[k] = P1[((size_t)(g * 16 + k) * BATCH + b) * SW + i];
#pragma unroll
    for (int k = 0; k < 16; ++k) {
      P1[((size_t)(g * 16 + k) * BATCH + b) * SW + i] = run;
      run += v[k];
    }
  }
}

// ---------------- stage 1c: prefix walk -> fp8 U + fp32 ULAST ----------------
__global__ __launch_bounds__(512) void k_s1c(const float* __restrict__ x,
                                             const int* __restrict__ IDXI,
                                             const float* __restrict__ P1,
                                             unsigned char* __restrict__ U,
                                             float* __restrict__ ULAST) {
  __shared__ float xs[16][IN_W] __attribute__((aligned(16)));
  __shared__ unsigned char us[16][SW] __attribute__((aligned(16)));
  __shared__ float ul[SW] __attribute__((aligned(16)));
  int c = blockIdx.x, b = blockIdx.y, tid = threadIdx.x;
  float v = P1[((size_t)c * BATCH + b) * SW + tid];
  int t0 = c * CLEN;
  int cur = IDXI[(size_t)t0 * SW + tid];
  for (int tt = 0; tt < CLEN; tt += 16) {
#pragma unroll
    for (int s = 0; s < 2; ++s) {
      int idx = s * 512 + tid;
      int row = idx >> 6, col = (idx & 63) * 4;
      *reinterpret_cast<f32x4*>(&xs[row][col]) =
          *reinterpret_cast<const f32x4*>(&x[((size_t)(t0 + tt + row) * BATCH + b) * IN_W + col]);
    }
    __syncthreads();
#pragma unroll
    for (int k = 0; k < 16; ++k) {
      int t = t0 + tt + k;
      int nxt = IDXI[(size_t)(t + 1) * SW + tid];
      if (cur < IN_W) v += xs[k][cur];
      us[k][nxt] = f8cvt(v);
      if (t == T_STEPS - 1) ul[nxt] = v;
      cur = nxt;
    }
    __syncthreads();
    {  // dump 16 rows x 512 fp8 = 512 int4, 1 per thread
      int row = tid >> 5, g = tid & 31;
      *reinterpret_cast<int4*>(U + ((size_t)(t0 + tt + row) * BATCH + b) * SW + g * 16) =
          *reinterpret_cast<const int4*>(&us[row][g * 16]);
    }
    __syncthreads();
  }
  if (c == NCHUNK - 1) ULAST[(size_t)b * SW + tid] = ul[tid];
}

// ---------------- FUSED MLP: phase-1 fp8, phase-2 bf16, fp8 F out ------------
__global__ __launch_bounds__(512, 2) void k_mlp(const unsigned char* __restrict__ A,
                                                const unsigned char* __restrict__ W1,
                                                const __hip_bfloat16* __restrict__ W2,
                                                const float* __restrict__ b1,
                                                const float* __restrict__ b2,
                                                unsigned char* __restrict__ Fout) {
  __shared__ unsigned char smem[81920] __attribute__((aligned(16)));
  const int tid = threadIdx.x;
  const int lane = tid & 63;
  const int wv = tid >> 6;
  const int hwr = wv >> 1, hwc = wv & 1;   // phase-1 grid 4x2 (32x64 tiles)
  const int fwr = wv >> 2, fwc = wv & 3;   // phase-2 grid 2x4 (64x32 tiles)
  const size_t m0 = (size_t)blockIdx.x * 128;
  unsigned short* Hs = reinterpret_cast<unsigned short*>(smem + 49152);

  f32x4 Facc[4][4][2];                     // [n-quarter][m][n]
#pragma unroll
  for (int q = 0; q < 4; ++q)
#pragma unroll
    for (int m = 0; m < 4; ++m)
#pragma unroll
      for (int n = 0; n < 2; ++n) Facc[q][m][n] = (f32x4)0.f;

  for (int hb = 0; hb < 4; ++hb) {
    f32x4 Hacc[2][4];
#pragma unroll
    for (int m = 0; m < 2; ++m)
#pragma unroll
      for (int n = 0; n < 4; ++n) Hacc[m][n] = (f32x4)0.f;

    // ---- phase 1 (fp8): depth-3 pipeline, 2 loads/thread/stage ----
    auto stage1 = [&](int kt, int buf) {
      int row = tid >> 2, pg = tid & 3;
      int sg = pg ^ ((row >> 2) & 3);
      gload_lds16(A + (m0 + row) * 512 + kt * 64 + sg * 16,
                  (const char*)smem + buf * 8192 + tid * 16);
      gload_lds16(W1 + (size_t)(hb * 128 + row) * 512 + kt * 64 + sg * 16,
                  (const char*)smem + 24576 + buf * 8192 + tid * 16);
    };
    stage1(0, 0);
    stage1(1, 1);
#pragma unroll
    for (int kt = 0; kt < 8; ++kt) {
      if (kt < 7) asm volatile("s_waitcnt vmcnt(2)" ::: "memory");
      else        asm volatile("s_waitcnt vmcnt(0)" ::: "memory");
      __builtin_amdgcn_s_barrier();
      if (kt < 6) stage1(kt + 2, (kt + 2) % 3);
      const unsigned char* Ab = smem + (kt % 3) * 8192;
      const unsigned char* W1b_ = smem + 24576 + (kt % 3) * 8192;
#pragma unroll
      for (int kh = 0; kh < 2; ++kh) {
        long af[2], bfw[4];
        int g = kh * 4 + (lane >> 4);
#pragma unroll
        for (int m = 0; m < 2; ++m) {
          int row = hwr * 32 + m * 16 + (lane & 15);
          int off = row * 64 + ((((g >> 1) ^ ((row >> 2) & 3)) << 4) | ((g & 1) << 3));
          af[m] = *reinterpret_cast<const long*>(Ab + off);
        }
#pragma unroll
        for (int n = 0; n < 4; ++n) {
          int row = hwc * 64 + n * 16 + (lane & 15);
          int off = row * 64 + ((((g >> 1) ^ ((row >> 2) & 3)) << 4) | ((g & 1) << 3));
          bfw[n] = *reinterpret_cast<const long*>(W1b_ + off);
        }
#pragma unroll
        for (int m = 0; m < 2; ++m)
#pragma unroll
          for (int n = 0; n < 4; ++n)
            Hacc[m][n] = __builtin_amdgcn_mfma_f32_16x16x32_fp8_fp8(af[m], bfw[n], Hacc[m][n], 0, 0, 0);
      }
    }
    __syncthreads();  // all phase-1 LDS reads done

    // issue W2 round-0 (128 N-rows x 64 k bf16 = 16KB) into W2 buf 0 [0,16K)
    {
#pragma unroll
      for (int s = 0; s < 2; ++s) {
        int idx = s * 512 + tid;          // 1024 granules (128 rows x 8 of 16B)
        int row = idx >> 3, pg = idx & 7;
        int sg = pg ^ (row & 7);
        gload_lds16(W2 + (size_t)row * 512 + hb * 128 + sg * 8,
                    (const char*)smem + idx * 16);
      }
    }

    // Hacc + b1 -> relu -> bf16 Hs [128 rows][16 granules], phys = hg^(row&15)
    {
      const int rl = (lane >> 4) * 4;
      const int cl = lane & 15;
#pragma unroll
      for (int m = 0; m < 2; ++m)
#pragma unroll
        for (int n = 0; n < 4; ++n) {
          int coll = hwc * 64 + n * 16 + cl;
          float bv = b1[hb * 128 + coll];
#pragma unroll
          for (int r = 0; r < 4; ++r) {
            int rowl = hwr * 32 + m * 16 + rl + r;
            float h = Hacc[m][n][r] + bv;
            h = h > 0.f ? h : 0.f;
            int phys = (coll >> 3) ^ (rowl & 15);
            Hs[rowl * 128 + phys * 8 + (coll & 7)] = bf16bits(h);
          }
        }
    }
    __syncthreads();  // drains W2 round-0 + Hs writes

    // ---- phase 2 (bf16): 8 rounds r=(nh2=r>>1, ks=r&1), W2 tri-buffer ----
#pragma unroll
    for (int r = 0; r < 8; ++r) {
      if (r < 7) {
        int rn = r + 1;
        int nh2n = rn >> 1, ksn = rn & 1;
        int regbyte = (rn % 3) * 16384;
#pragma unroll
        for (int s = 0; s < 2; ++s) {
          int idx = s * 512 + tid;
          int row = idx >> 3, pg = idx & 7;
          int sg = pg ^ (row & 7);
          gload_lds16(W2 + (size_t)(nh2n * 128 + row) * 512 + hb * 128 + ksn * 64 + sg * 8,
                      (const char*)smem + regbyte + idx * 16);
        }
      }
      if (r > 0) {
        if (r < 7) asm volatile("s_waitcnt vmcnt(2)" ::: "memory");
        else       asm volatile("s_waitcnt vmcnt(0)" ::: "memory");
        __builtin_amdgcn_s_barrier();
      }
      const int nh2 = r >> 1, ks = r & 1;
      const unsigned short* w2b =
          reinterpret_cast<const unsigned short*>(smem + (r % 3) * 16384);
#pragma unroll
      for (int kh = 0; kh < 2; ++kh) {
        bf16x8 afH[4], bf2[2];
#pragma unroll
        for (int m = 0; m < 4; ++m) {
          int row = fwr * 64 + m * 16 + (lane & 15);
          int hg = ks * 8 + kh * 4 + (lane >> 4);
          int phys = hg ^ (row & 15);
          afH[m] = *reinterpret_cast<const bf16x8*>(&Hs[row * 128 + phys * 8]);
        }
#pragma unroll
        for (int n = 0; n < 2; ++n) {
          int row = fwc * 32 + n * 16 + (lane & 15);   // N within 128-quarter
          int lg = kh * 4 + (lane >> 4);
          int phys = lg ^ (row & 7);
          bf2[n] = *reinterpret_cast<const bf16x8*>(&w2b[row * 64 + phys * 8]);
        }
#pragma unroll
        for (int m = 0; m < 4; ++m)
#pragma unroll
          for (int n = 0; n < 2; ++n)
            Facc[nh2][m][n] = __builtin_amdgcn_mfma_f32_16x16x32_bf16(afH[m], bf2[n], Facc[nh2][m][n], 0, 0, 0);
      }
    }
    __syncthreads();  // phase-2 LDS reads done before next hb / epilogue
  }

  // ---- F epilogue (fp8): Facc + b2 -> scratch [128][256B] -> int2 stores ----
  const int rl = (lane >> 4) * 4;
  const int cl = lane & 15;
#pragma unroll
  for (int p = 0; p < 2; ++p) {      // col halves: quarters {2p, 2p+1}
#pragma unroll
    for (int qh = 0; qh < 2; ++qh) {
      int q = 2 * p + qh;
#pragma unroll
      for (int m = 0; m < 4; ++m)
#pragma unroll
        for (int n = 0; n < 2; ++n) {
          int coll = qh * 128 + fwc * 32 + n * 16 + cl;   // byte col within 256
          float bv = b2[p * 256 + coll];
#pragma unroll
          for (int r = 0; r < 4; ++r) {
            int rowl = fwr * 64 + m * 16 + rl + r;
            float v = Facc[q][m][n][r] + bv;
            int phys = (coll >> 3) ^ (rowl & 31);         // 32 8B-granules/row
            smem[rowl * 256 + phys * 8 + (coll & 7)] = f8cvt(v);
          }
        }
    }
    __syncthreads();
#pragma unroll
    for (int s = 0; s < 8; ++s) {
      int idx = s * 512 + tid;                            // 4096 = 128r x 32g
      int rowl = idx >> 5, g = idx & 31;
      int phys = g ^ (rowl & 31);
      *reinterpret_cast<int2*>(Fout + (m0 + rowl) * 512 + p * 256 + g * 8) =
          *reinterpret_cast<const int2*>(smem + rowl * 256 + phys * 8);
    }
    __syncthreads();
  }
}

// ---------------- stage 3a: 16-deep staged byte gather (fp8 F) ---------------
__global__ __launch_bounds__(512) void k_s3a(const unsigned char* __restrict__ F,
                                             const int* __restrict__ IDXI,
                                             float* __restrict__ P3) {
  __shared__ unsigned char fs[16][SW] __attribute__((aligned(16)));
  int c = blockIdx.x, b = blockIdx.y, tid = threadIdx.x;
  float acc = 0.f;
  int t0 = c * CLEN;
  for (int tt = 0; tt < CLEN; tt += 16) {
    {  // 16 rows x 512 fp8 = 512 int4, 1 per thread, coalesced
      int row = tid >> 5, g = tid & 31;
      *reinterpret_cast<int4*>(&fs[row][g * 16]) =
          *reinterpret_cast<const int4*>(&F[((size_t)(t0 + tt + row) * BATCH + b) * SW + g * 16]);
    }
    __syncthreads();
#pragma unroll
    for (int k = 0; k < 16; ++k) {
      int t = t0 + tt + k;
      if (t < T_STEPS - 1) {
        int i0 = IDXI[(size_t)t * SW + tid];
        acc += f8val(fs[k][i0]);
      }
    }
    __syncthreads();
  }
  P3[((size_t)c * BATCH + b) * SW + tid] = acc;
}

// ---------------- exact fp32 final step (+ fused s3b) ------------------------
__global__ __launch_bounds__(512) void k_final(const float* __restrict__ P3,
                                               const int* __restrict__ FW,
                                               const float* __restrict__ ULAST,
                                               const float* __restrict__ W1,
                                               const float* __restrict__ b1,
                                               const float* __restrict__ W2,
                                               const float* __restrict__ b2,
                                               float* __restrict__ out) {
  __shared__ float ml[SW] __attribute__((aligned(16)));
  __shared__ float uc[SW] __attribute__((aligned(16)));
  __shared__ float hh[SW] __attribute__((aligned(16)));
  int b = blockIdx.x, j = threadIdx.x;
  float s = 0.f;
  for (int c = 0; c < NCHUNK; ++c) s += P3[((size_t)c * BATCH + b) * SW + j];
  ml[j] = s;
  __syncthreads();
  float e = ml[FW[(size_t)(T_STEPS - 1) * SW + j]];
  float u = ULAST[(size_t)b * SW + j] + EPS * e;
  uc[j] = u;
  __syncthreads();
  float pre = b1[j];
  {
    const f32x4* wr = (const f32x4*)(W1 + (size_t)j * SW);
    const f32x4* uv = (const f32x4*)uc;
    for (int k = 0; k < SW / 4; ++k) {
      f32x4 wv = wr[k], vv = uv[k];
      pre += wv[0] * vv[0] + wv[1] * vv[1] + wv[2] * vv[2] + wv[3] * vv[3];
    }
  }
  hh[j] = pre > 0.f ? pre : 0.f;
  __syncthreads();
  float d = b2[j];
  {
    const f32x4* wr = (const f32x4*)(W2 + (size_t)j * SW);
    const f32x4* hv = (const f32x4*)hh;
    for (int k = 0; k < SW / 4; ++k) {
      f32x4 wv = wr[k], vv = hv[k];
      d += wv[0] * vv[0] + wv[1] * vv[1] + wv[2] * vv[2] + wv[3] * vv[3];
    }
  }
  float sT = u + EPS * d;
  out[BATCH * 128 + (size_t)b * SW + j] = sT;                // last  [64,512]
  if (j >= SW - 128) out[b * 128 + (j - (SW - 128))] = sT;   // outputs [64,128]
}

// ---------------- host -------------------------------------------------------
extern "C" void kernel_launch(void* const* d_in, const int* in_sizes, int n_in,
                              void* d_out, int out_size, void* d_ws, size_t ws_size,
                              hipStream_t stream) {
  const float* x = (const float*)d_in[0];
  const float* init = (const float*)d_in[1];
  const float* W1 = (const float*)d_in[2];
  const float* b1 = (const float*)d_in[3];
  const float* W2 = (const float*)d_in[4];
  const float* b2 = (const float*)d_in[5];
  const int* perm = (const int*)d_in[6];
  float* out = (float*)d_out;

  char* w = (char*)d_ws;
  size_t off = 0;
  auto alloc = [&](size_t bytes) {
    size_t o = off;
    off = (off + bytes + 255) & ~(size_t)255;
    return o;
  };
  size_t oFW   = alloc((size_t)(T_STEPS + 1) * SW * 4);
  size_t oIDXI = alloc((size_t)(T_STEPS + 1) * SW * 4);
  size_t oFWQ  = alloc((size_t)NQ * SW * 4);
  size_t oIDXQ = alloc((size_t)NQ * SW * 4);
  size_t oW1q  = alloc((size_t)SW * SW);
  size_t oW2b  = alloc((size_t)SW * SW * 2);
  size_t oU    = alloc((size_t)T_STEPS * BATCH * SW);      // fp8
  size_t oF    = alloc((size_t)T_STEPS * BATCH * SW);      // fp8
  size_t oP1   = alloc((size_t)NCHUNK * BATCH * SW * 4);
  size_t oP3   = alloc((size_t)NCHUNK * BATCH * SW * 4);
  size_t oUL   = alloc((size_t)BATCH * SW * 4);
  if (off > ws_size) return;

  int* FW = (int*)(w + oFW);
  int* IDXI = (int*)(w + oIDXI);
  int* FWQ = (int*)(w + oFWQ);
  int* IDXIQ = (int*)(w + oIDXQ);
  unsigned char* W1q = (unsigned char*)(w + oW1q);
  __hip_bfloat16* W2b = (__hip_bfloat16*)(w + oW2b);
  unsigned char* U = (unsigned char*)(w + oU);
  unsigned char* F = (unsigned char*)(w + oF);
  float* P1 = (float*)(w + oP1);
  float* P3 = (float*)(w + oP3);
  float* ULAST = (float*)(w + oUL);

  k_tabA<<<1, 512, 0, stream>>>(perm, FW, IDXI);
  k_tabB<<<1, 512, 0, stream>>>(FW, IDXI, FWQ, IDXIQ);
  k_tabC<<<T_STEPS + 1, 512, 0, stream>>>(FWQ, IDXIQ, FW, IDXI);
  k_wcast<<<(2 * SW * SW + 255) / 256, 256, 0, stream>>>(W1, W2, W1q, W2b);

  k_s1a<<<dim3(NCHUNK, BATCH), 512, 0, stream>>>(x, IDXI, P1);
  k_s1b<<<BATCH, 512, 0, stream>>>(init, P1);
  k_s1c<<<dim3(NCHUNK, BATCH), 512, 0, stream>>>(x, IDXI, P1, U, ULAST);

  k_mlp<<<(T_STEPS * BATCH) / 128, 512, 0, stream>>>(U, W1q, W2b, b1, b2, F);

  k_s3a<<<dim3(NCHUNK, BATCH), 512, 0, stream>>>(F, IDXI, P3);

  k_final<<<BATCH, 512, 0, stream>>>(P3, FW, ULAST, W1, b1, W2, b2, out);
}

// Round 18
// 357.546 us; speedup vs baseline: 1.6676x; 1.0387x over previous
//
#include <hip/hip_runtime.h>
#include <hip/hip_bf16.h>
#include <stdint.h>

// ResRnn via first-order expansion in eps (method err ~1e-3 << 2.62):
//   tables: pi^t / pi^-t via composition doubling (+ u16 copy of IDXI)
//   stage1: permuted prefix sum -> U (fp8 e4m3, HW cvt) + ULAST (fp32)
//   k_mlp : FUSED F = relu(U@W1^T+b1)@W2^T + b2  [phase 1 fp8, phase 2 bf16,
//           depth-3 vmcnt pipes; F stored fp8]  (r17 frozen)
//   stage3: e-reduction register gather over fp8 F, 16-deep staging
//   final : exact fp32 last step (+ fused s3b).

#define T_STEPS 2048
#define BATCH 64
#define IN_W 256
#define SW 512
#define EPS 1e-5f
#define NCHUNK 64
#define CLEN 32
#define QSTEP 32
#define NQ 65

typedef __bf16 bf16x8 __attribute__((ext_vector_type(8)));
typedef float f32x4 __attribute__((ext_vector_type(4)));

__device__ __forceinline__ unsigned short bf16bits(float v) {
  __hip_bfloat16 h = __float2bfloat16(v);
  return *reinterpret_cast<unsigned short*>(&h);
}

__device__ __forceinline__ float bf16val(unsigned short u) {
  unsigned int x = ((unsigned int)u) << 16;
  return __uint_as_float(x);
}

// float -> OCP e4m3 via HW v_cvt_pk_fp8_f32 (RNE, saturating)
__device__ __forceinline__ unsigned char f8cvt(float v) {
  return (unsigned char)(__builtin_amdgcn_cvt_pk_fp8_f32(v, v, 0, false) & 0xff);
}
// e4m3 byte -> float via HW v_cvt_f32_fp8
__device__ __forceinline__ float f8val(unsigned char u) {
  return __builtin_amdgcn_cvt_f32_fp8((int)u, 0);
}

__device__ __forceinline__ void gload_lds16(const void* g, const void* l) {
  __builtin_amdgcn_global_load_lds(
      (const __attribute__((address_space(1))) unsigned int*)(uintptr_t)g,
      (__attribute__((address_space(3))) unsigned int*)(uintptr_t)l, 16, 0, 0);
}

// ---------------- permutation power tables (doubling) ------------------------
__global__ __launch_bounds__(512) void k_tabA(const int* __restrict__ perm,
                                              int* __restrict__ FW, int* __restrict__ IDXI) {
  __shared__ int pl[SW], il[SW];
  int j = threadIdx.x;
  pl[j] = perm[j];
  __syncthreads();
  il[pl[j]] = j;
  __syncthreads();
  int f = j, iv = j;
  FW[j] = f; IDXI[j] = iv;
  for (int t = 1; t <= QSTEP; ++t) {
    f = pl[f]; iv = il[iv];
    FW[t * SW + j] = f; IDXI[t * SW + j] = iv;
  }
}

__global__ __launch_bounds__(512) void k_tabB(const int* __restrict__ FW, const int* __restrict__ IDXI,
                                              int* __restrict__ FWQ, int* __restrict__ IDXIQ) {
  __shared__ int f32r[SW], i32r[SW];
  int j = threadIdx.x;
  f32r[j] = FW[QSTEP * SW + j];
  i32r[j] = IDXI[QSTEP * SW + j];
  __syncthreads();
  int f = j, iv = j;
  FWQ[j] = f; IDXIQ[j] = iv;
  for (int q = 1; q < NQ; ++q) {
    f = f32r[f]; iv = i32r[iv];
    FWQ[q * SW + j] = f; IDXIQ[q * SW + j] = iv;
  }
}

__global__ __launch_bounds__(512) void k_tabC(const int* __restrict__ FWQ, const int* __restrict__ IDXIQ,
                                              int* __restrict__ FW, int* __restrict__ IDXI) {
  int t = blockIdx.x;
  if (t <= QSTEP) return;
  int j = threadIdx.x;
  int q = t >> 5, r = t & 31;
  int a = FW[r * SW + j];
  FW[(size_t)t * SW + j] = FWQ[q * SW + a];
  int b = IDXI[r * SW + j];
  IDXI[(size_t)t * SW + j] = IDXIQ[q * SW + b];
}

// IDXI (int) -> IDXI16 (ushort): 2.1 MB table, fully L2-resident
__global__ __launch_bounds__(512) void k_tab16(const int* __restrict__ IDXI,
                                               unsigned short* __restrict__ IDXI16) {
  size_t i = (size_t)blockIdx.x * 512 + threadIdx.x;
  IDXI16[i] = (unsigned short)IDXI[i];
}

// ---------------- weights: W1 -> fp8 (HW cvt), W2 -> bf16 --------------------
__global__ __launch_bounds__(256) void k_wcast(const float* __restrict__ W1,
                                               const float* __restrict__ W2,
                                               unsigned char* __restrict__ W1q,
                                               __hip_bfloat16* __restrict__ W2b) {
  int i = blockIdx.x * 256 + threadIdx.x;
  if (i < SW * SW) W1q[i] = f8cvt(W1[i]);
  else W2b[i - SW * SW] = __float2bfloat16(W2[i - SW * SW]);
}

// ---------------- stage 1a: chunk sums, 16-deep staged register gather -------
__global__ __launch_bounds__(512) void k_s1a(const float* __restrict__ x,
                                             const unsigned short* __restrict__ IDXI16,
                                             float* __restrict__ P1) {
  __shared__ float xs[16][IN_W] __attribute__((aligned(16)));
  int c = blockIdx.x, b = blockIdx.y, tid = threadIdx.x;
  float acc = 0.f;
  int t0 = c * CLEN;
  for (int tt = 0; tt < CLEN; tt += 16) {
#pragma unroll
    for (int s = 0; s < 2; ++s) {
      int idx = s * 512 + tid;
      int row = idx >> 6, col = (idx & 63) * 4;
      *reinterpret_cast<f32x4*>(&xs[row][col]) =
          *reinterpret_cast<const f32x4*>(&x[((size_t)(t0 + tt + row) * BATCH + b) * IN_W + col]);
    }
    __syncthreads();
#pragma unroll
    for (int k = 0; k < 16; ++k) {
      int i0 = IDXI16[(size_t)(t0 + tt + k) * SW + tid];
      if (i0 < IN_W) acc += xs[k][i0];
    }
    __syncthreads();
  }
  P1[((size_t)c * BATCH + b) * SW + tid] = acc;
}

// ---------------- stage 1b: chunk scan, 16-deep batched loads ----------------
__global__ __launch_bounds__(512) void k_s1b(const float* __restrict__ init,
                                             float* __restrict__ P1) {
  int b = blockIdx.x, i = threadIdx.x;
  float run = EPS * init[i];
  float v[16];
  for (int g = 0; g < NCHUNK / 16; ++g) {
#pragma unroll
    for (int k = 0; k < 16; ++k)
      v[k] = P1[((size_t)(g * 16 + k) * BATCH + b) * SW + i];
#pragma unroll
    for (int k = 0; k < 16; ++k) {
      P1[((size_t)(g * 16 + k) * BATCH + b) * SW + i] = run;
      run += v[k];
    }
  }
}

// ---------------- stage 1c: prefix walk -> fp8 U + fp32 ULAST ----------------
__global__ __launch_bounds__(512) void k_s1c(const float* __restrict__ x,
                                             const unsigned short* __restrict__ IDXI16,
                                             const float* __restrict__ P1,
                                             unsigned char* __restrict__ U,
                                             float* __restrict__ ULAST) {
  __shared__ float xs[16][IN_W] __attribute__((aligned(16)));
  __shared__ unsigned char us[16][SW] __attribute__((aligned(16)));
  __shared__ float ul[SW] __attribute__((aligned(16)));
  int c = blockIdx.x, b = blockIdx.y, tid = threadIdx.x;
  float v = P1[((size_t)c * BATCH + b) * SW + tid];
  int t0 = c * CLEN;
  int cur = IDXI16[(size_t)t0 * SW + tid];
  for (int tt = 0; tt < CLEN; tt += 16) {
#pragma unroll
    for (int s = 0; s < 2; ++s) {
      int idx = s * 512 + tid;
      int row = idx >> 6, col = (idx & 63) * 4;
      *reinterpret_cast<f32x4*>(&xs[row][col]) =
          *reinterpret_cast<const f32x4*>(&x[((size_t)(t0 + tt + row) * BATCH + b) * IN_W + col]);
    }
    __syncthreads();
#pragma unroll
    for (int k = 0; k < 16; ++k) {
      int t = t0 + tt + k;
      int nxt = IDXI16[(size_t)(t + 1) * SW + tid];
      if (cur < IN_W) v += xs[k][cur];
      us[k][nxt] = f8cvt(v);
      if (t == T_STEPS - 1) ul[nxt] = v;
      cur = nxt;
    }
    __syncthreads();
    {  // dump 16 rows x 512 fp8 = 512 int4, 1 per thread
      int row = tid >> 5, g = tid & 31;
      *reinterpret_cast<int4*>(U + ((size_t)(t0 + tt + row) * BATCH + b) * SW + g * 16) =
          *reinterpret_cast<const int4*>(&us[row][g * 16]);
    }
    __syncthreads();
  }
  if (c == NCHUNK - 1) ULAST[(size_t)b * SW + tid] = ul[tid];
}

// ---------------- FUSED MLP (round-17 verbatim, frozen) ----------------------
__global__ __launch_bounds__(512, 2) void k_mlp(const unsigned char* __restrict__ A,
                                                const unsigned char* __restrict__ W1,
                                                const __hip_bfloat16* __restrict__ W2,
                                                const float* __restrict__ b1,
                                                const float* __restrict__ b2,
                                                unsigned char* __restrict__ Fout) {
  __shared__ unsigned char smem[81920] __attribute__((aligned(16)));
  const int tid = threadIdx.x;
  const int lane = tid & 63;
  const int wv = tid >> 6;
  const int hwr = wv >> 1, hwc = wv & 1;   // phase-1 grid 4x2 (32x64 tiles)
  const int fwr = wv >> 2, fwc = wv & 3;   // phase-2 grid 2x4 (64x32 tiles)
  const size_t m0 = (size_t)blockIdx.x * 128;
  unsigned short* Hs = reinterpret_cast<unsigned short*>(smem + 49152);

  f32x4 Facc[4][4][2];                     // [n-quarter][m][n]
#pragma unroll
  for (int q = 0; q < 4; ++q)
#pragma unroll
    for (int m = 0; m < 4; ++m)
#pragma unroll
      for (int n = 0; n < 2; ++n) Facc[q][m][n] = (f32x4)0.f;

  for (int hb = 0; hb < 4; ++hb) {
    f32x4 Hacc[2][4];
#pragma unroll
    for (int m = 0; m < 2; ++m)
#pragma unroll
      for (int n = 0; n < 4; ++n) Hacc[m][n] = (f32x4)0.f;

    // ---- phase 1 (fp8): depth-3 pipeline, 2 loads/thread/stage ----
    auto stage1 = [&](int kt, int buf) {
      int row = tid >> 2, pg = tid & 3;
      int sg = pg ^ ((row >> 2) & 3);
      gload_lds16(A + (m0 + row) * 512 + kt * 64 + sg * 16,
                  (const char*)smem + buf * 8192 + tid * 16);
      gload_lds16(W1 + (size_t)(hb * 128 + row) * 512 + kt * 64 + sg * 16,
                  (const char*)smem + 24576 + buf * 8192 + tid * 16);
    };
    stage1(0, 0);
    stage1(1, 1);
#pragma unroll
    for (int kt = 0; kt < 8; ++kt) {
      if (kt < 7) asm volatile("s_waitcnt vmcnt(2)" ::: "memory");
      else        asm volatile("s_waitcnt vmcnt(0)" ::: "memory");
      __builtin_amdgcn_s_barrier();
      if (kt < 6) stage1(kt + 2, (kt + 2) % 3);
      const unsigned char* Ab = smem + (kt % 3) * 8192;
      const unsigned char* W1b_ = smem + 24576 + (kt % 3) * 8192;
#pragma unroll
      for (int kh = 0; kh < 2; ++kh) {
        long af[2], bfw[4];
        int g = kh * 4 + (lane >> 4);
#pragma unroll
        for (int m = 0; m < 2; ++m) {
          int row = hwr * 32 + m * 16 + (lane & 15);
          int off = row * 64 + ((((g >> 1) ^ ((row >> 2) & 3)) << 4) | ((g & 1) << 3));
          af[m] = *reinterpret_cast<const long*>(Ab + off);
        }
#pragma unroll
        for (int n = 0; n < 4; ++n) {
          int row = hwc * 64 + n * 16 + (lane & 15);
          int off = row * 64 + ((((g >> 1) ^ ((row >> 2) & 3)) << 4) | ((g & 1) << 3));
          bfw[n] = *reinterpret_cast<const long*>(W1b_ + off);
        }
#pragma unroll
        for (int m = 0; m < 2; ++m)
#pragma unroll
          for (int n = 0; n < 4; ++n)
            Hacc[m][n] = __builtin_amdgcn_mfma_f32_16x16x32_fp8_fp8(af[m], bfw[n], Hacc[m][n], 0, 0, 0);
      }
    }
    __syncthreads();  // all phase-1 LDS reads done

    // issue W2 round-0 (128 N-rows x 64 k bf16 = 16KB) into W2 buf 0 [0,16K)
    {
#pragma unroll
      for (int s = 0; s < 2; ++s) {
        int idx = s * 512 + tid;          // 1024 granules (128 rows x 8 of 16B)
        int row = idx >> 3, pg = idx & 7;
        int sg = pg ^ (row & 7);
        gload_lds16(W2 + (size_t)row * 512 + hb * 128 + sg * 8,
                    (const char*)smem + idx * 16);
      }
    }

    // Hacc + b1 -> relu -> bf16 Hs [128 rows][16 granules], phys = hg^(row&15)
    {
      const int rl = (lane >> 4) * 4;
      const int cl = lane & 15;
#pragma unroll
      for (int m = 0; m < 2; ++m)
#pragma unroll
        for (int n = 0; n < 4; ++n) {
          int coll = hwc * 64 + n * 16 + cl;
          float bv = b1[hb * 128 + coll];
#pragma unroll
          for (int r = 0; r < 4; ++r) {
            int rowl = hwr * 32 + m * 16 + rl + r;
            float h = Hacc[m][n][r] + bv;
            h = h > 0.f ? h : 0.f;
            int phys = (coll >> 3) ^ (rowl & 15);
            Hs[rowl * 128 + phys * 8 + (coll & 7)] = bf16bits(h);
          }
        }
    }
    __syncthreads();  // drains W2 round-0 + Hs writes

    // ---- phase 2 (bf16): 8 rounds r=(nh2=r>>1, ks=r&1), W2 tri-buffer ----
#pragma unroll
    for (int r = 0; r < 8; ++r) {
      if (r < 7) {
        int rn = r + 1;
        int nh2n = rn >> 1, ksn = rn & 1;
        int regbyte = (rn % 3) * 16384;
#pragma unroll
        for (int s = 0; s < 2; ++s) {
          int idx = s * 512 + tid;
          int row = idx >> 3, pg = idx & 7;
          int sg = pg ^ (row & 7);
          gload_lds16(W2 + (size_t)(nh2n * 128 + row) * 512 + hb * 128 + ksn * 64 + sg * 8,
                      (const char*)smem + regbyte + idx * 16);
        }
      }
      if (r > 0) {
        if (r < 7) asm volatile("s_waitcnt vmcnt(2)" ::: "memory");
        else       asm volatile("s_waitcnt vmcnt(0)" ::: "memory");
        __builtin_amdgcn_s_barrier();
      }
      const int nh2 = r >> 1, ks = r & 1;
      const unsigned short* w2b =
          reinterpret_cast<const unsigned short*>(smem + (r % 3) * 16384);
#pragma unroll
      for (int kh = 0; kh < 2; ++kh) {
        bf16x8 afH[4], bf2[2];
#pragma unroll
        for (int m = 0; m < 4; ++m) {
          int row = fwr * 64 + m * 16 + (lane & 15);
          int hg = ks * 8 + kh * 4 + (lane >> 4);
          int phys = hg ^ (row & 15);
          afH[m] = *reinterpret_cast<const bf16x8*>(&Hs[row * 128 + phys * 8]);
        }
#pragma unroll
        for (int n = 0; n < 2; ++n) {
          int row = fwc * 32 + n * 16 + (lane & 15);   // N within 128-quarter
          int lg = kh * 4 + (lane >> 4);
          int phys = lg ^ (row & 7);
          bf2[n] = *reinterpret_cast<const bf16x8*>(&w2b[row * 64 + phys * 8]);
        }
#pragma unroll
        for (int m = 0; m < 4; ++m)
#pragma unroll
          for (int n = 0; n < 2; ++n)
            Facc[nh2][m][n] = __builtin_amdgcn_mfma_f32_16x16x32_bf16(afH[m], bf2[n], Facc[nh2][m][n], 0, 0, 0);
      }
    }
    __syncthreads();  // phase-2 LDS reads done before next hb / epilogue
  }

  // ---- F epilogue (fp8): Facc + b2 -> scratch [128][256B] -> int2 stores ----
  const int rl = (lane >> 4) * 4;
  const int cl = lane & 15;
#pragma unroll
  for (int p = 0; p < 2; ++p) {      // col halves: quarters {2p, 2p+1}
#pragma unroll
    for (int qh = 0; qh < 2; ++qh) {
      int q = 2 * p + qh;
#pragma unroll
      for (int m = 0; m < 4; ++m)
#pragma unroll
        for (int n = 0; n < 2; ++n) {
          int coll = qh * 128 + fwc * 32 + n * 16 + cl;   // byte col within 256
          float bv = b2[p * 256 + coll];
#pragma unroll
          for (int r = 0; r < 4; ++r) {
            int rowl = fwr * 64 + m * 16 + rl + r;
            float v = Facc[q][m][n][r] + bv;
            int phys = (coll >> 3) ^ (rowl & 31);         // 32 8B-granules/row
            smem[rowl * 256 + phys * 8 + (coll & 7)] = f8cvt(v);
          }
        }
    }
    __syncthreads();
#pragma unroll
    for (int s = 0; s < 8; ++s) {
      int idx = s * 512 + tid;                            // 4096 = 128r x 32g
      int rowl = idx >> 5, g = idx & 31;
      int phys = g ^ (rowl & 31);
      *reinterpret_cast<int2*>(Fout + (m0 + rowl) * 512 + p * 256 + g * 8) =
          *reinterpret_cast<const int2*>(smem + rowl * 256 + phys * 8);
    }
    __syncthreads();
  }
}

// ---------------- stage 3a: 16-deep staged byte gather (fp8 F) ---------------
template <int LAST>
__global__ __launch_bounds__(512) void k_s3a(const unsigned char* __restrict__ F,
                                             const unsigned short* __restrict__ IDXI16,
                                             float* __restrict__ P3) {
  __shared__ unsigned char fs[16][SW] __attribute__((aligned(16)));
  int c = LAST ? (NCHUNK - 1) : blockIdx.x;
  int b = blockIdx.y, tid = threadIdx.x;
  float acc = 0.f;
  int t0 = c * CLEN;
  for (int tt = 0; tt < CLEN; tt += 16) {
    {  // 16 rows x 512 fp8 = 512 int4, 1 per thread, coalesced
      int row = tid >> 5, g = tid & 31;
      *reinterpret_cast<int4*>(&fs[row][g * 16]) =
          *reinterpret_cast<const int4*>(&F[((size_t)(t0 + tt + row) * BATCH + b) * SW + g * 16]);
    }
    __syncthreads();
    if (LAST) {
#pragma unroll
      for (int k = 0; k < 16; ++k) {
        int t = t0 + tt + k;
        if (t < T_STEPS - 1) {
          int i0 = IDXI16[(size_t)t * SW + tid];
          acc += f8val(fs[k][i0]);
        }
      }
    } else {
#pragma unroll
      for (int k = 0; k < 16; ++k) {
        int i0 = IDXI16[(size_t)(t0 + tt + k) * SW + tid];
        acc += f8val(fs[k][i0]);
      }
    }
    __syncthreads();
  }
  P3[((size_t)c * BATCH + b) * SW + tid] = acc;
}

// ---------------- exact fp32 final step (+ fused s3b) ------------------------
__global__ __launch_bounds__(512) void k_final(const float* __restrict__ P3,
                                               const int* __restrict__ FW,
                                               const float* __restrict__ ULAST,
                                               const float* __restrict__ W1,
                                               const float* __restrict__ b1,
                                               const float* __restrict__ W2,
                                               const float* __restrict__ b2,
                                               float* __restrict__ out) {
  __shared__ float ml[SW] __attribute__((aligned(16)));
  __shared__ float uc[SW] __attribute__((aligned(16)));
  __shared__ float hh[SW] __attribute__((aligned(16)));
  int b = blockIdx.x, j = threadIdx.x;
  float s = 0.f;
  for (int c = 0; c < NCHUNK; ++c) s += P3[((size_t)c * BATCH + b) * SW + j];
  ml[j] = s;
  __syncthreads();
  float e = ml[FW[(size_t)(T_STEPS - 1) * SW + j]];
  float u = ULAST[(size_t)b * SW + j] + EPS * e;
  uc[j] = u;
  __syncthreads();
  float pre = b1[j];
  {
    const f32x4* wr = (const f32x4*)(W1 + (size_t)j * SW);
    const f32x4* uv = (const f32x4*)uc;
    for (int k = 0; k < SW / 4; ++k) {
      f32x4 wv = wr[k], vv = uv[k];
      pre += wv[0] * vv[0] + wv[1] * vv[1] + wv[2] * vv[2] + wv[3] * vv[3];
    }
  }
  hh[j] = pre > 0.f ? pre : 0.f;
  __syncthreads();
  float d = b2[j];
  {
    const f32x4* wr = (const f32x4*)(W2 + (size_t)j * SW);
    const f32x4* hv = (const f32x4*)hh;
    for (int k = 0; k < SW / 4; ++k) {
      f32x4 wv = wr[k], vv = hv[k];
      d += wv[0] * vv[0] + wv[1] * vv[1] + wv[2] * vv[2] + wv[3] * vv[3];
    }
  }
  float sT = u + EPS * d;
  out[BATCH * 128 + (size_t)b * SW + j] = sT;                // last  [64,512]
  if (j >= SW - 128) out[b * 128 + (j - (SW - 128))] = sT;   // outputs [64,128]
}

// ---------------- host -------------------------------------------------------
extern "C" void kernel_launch(void* const* d_in, const int* in_sizes, int n_in,
                              void* d_out, int out_size, void* d_ws, size_t ws_size,
                              hipStream_t stream) {
  const float* x = (const float*)d_in[0];
  const float* init = (const float*)d_in[1];
  const float* W1 = (const float*)d_in[2];
  const float* b1 = (const float*)d_in[3];
  const float* W2 = (const float*)d_in[4];
  const float* b2 = (const float*)d_in[5];
  const int* perm = (const int*)d_in[6];
  float* out = (float*)d_out;

  char* w = (char*)d_ws;
  size_t off = 0;
  auto alloc = [&](size_t bytes) {
    size_t o = off;
    off = (off + bytes + 255) & ~(size_t)255;
    return o;
  };
  size_t oFW   = alloc((size_t)(T_STEPS + 1) * SW * 4);
  size_t oIDXI = alloc((size_t)(T_STEPS + 1) * SW * 4);
  size_t oI16  = alloc((size_t)(T_STEPS + 1) * SW * 2);
  size_t oFWQ  = alloc((size_t)NQ * SW * 4);
  size_t oIDXQ = alloc((size_t)NQ * SW * 4);
  size_t oW1q  = alloc((size_t)SW * SW);
  size_t oW2b  = alloc((size_t)SW * SW * 2);
  size_t oU    = alloc((size_t)T_STEPS * BATCH * SW);      // fp8
  size_t oF    = alloc((size_t)T_STEPS * BATCH * SW);      // fp8
  size_t oP1   = alloc((size_t)NCHUNK * BATCH * SW * 4);
  size_t oP3   = alloc((size_t)NCHUNK * BATCH * SW * 4);
  size_t oUL   = alloc((size_t)BATCH * SW * 4);
  if (off > ws_size) return;

  int* FW = (int*)(w + oFW);
  int* IDXI = (int*)(w + oIDXI);
  unsigned short* IDXI16 = (unsigned short*)(w + oI16);
  int* FWQ = (int*)(w + oFWQ);
  int* IDXIQ = (int*)(w + oIDXQ);
  unsigned char* W1q = (unsigned char*)(w + oW1q);
  __hip_bfloat16* W2b = (__hip_bfloat16*)(w + oW2b);
  unsigned char* U = (unsigned char*)(w + oU);
  unsigned char* F = (unsigned char*)(w + oF);
  float* P1 = (float*)(w + oP1);
  float* P3 = (float*)(w + oP3);
  float* ULAST = (float*)(w + oUL);

  k_tabA<<<1, 512, 0, stream>>>(perm, FW, IDXI);
  k_tabB<<<1, 512, 0, stream>>>(FW, IDXI, FWQ, IDXIQ);
  k_tabC<<<T_STEPS + 1, 512, 0, stream>>>(FWQ, IDXIQ, FW, IDXI);
  k_tab16<<<T_STEPS + 1, 512, 0, stream>>>(IDXI, IDXI16);
  k_wcast<<<(2 * SW * SW + 255) / 256, 256, 0, stream>>>(W1, W2, W1q, W2b);

  k_s1a<<<dim3(NCHUNK, BATCH), 512, 0, stream>>>(x, IDXI16, P1);
  k_s1b<<<BATCH, 512, 0, stream>>>(init, P1);
  k_s1c<<<dim3(NCHUNK, BATCH), 512, 0, stream>>>(x, IDXI16, P1, U, ULAST);

  k_mlp<<<(T_STEPS * BATCH) / 128, 512, 0, stream>>>(U, W1q, W2b, b1, b2, F);

  k_s3a<0><<<dim3(NCHUNK - 1, BATCH), 512, 0, stream>>>(F, IDXI16, P3);
  k_s3a<1><<<dim3(1, BATCH), 512, 0, stream>>>(F, IDXI16, P3);

  k_final<<<BATCH, 512, 0, stream>>>(P3, FW, ULAST, W1, b1, W2, b2, out);
}

// Round 19
// 334.316 us; speedup vs baseline: 1.7834x; 1.0695x over previous
//
#include <hip/hip_runtime.h>
#include <hip/hip_bf16.h>
#include <stdint.h>

// ResRnn via first-order expansion in eps (method err ~1e-3 << 2.62):
//   tables: pi^t / pi^-t via composition doubling (+ u16 copy of IDXI)
//   stage1: permuted prefix sum -> U (fp8 e4m3, HW cvt) + ULAST (fp32)
//           [s1a: 4-batch-per-block index-amortized gather]
//   k_mlp : FUSED F = relu(U@W1^T+b1)@W2^T + b2  (r17 frozen)
//   stage3: e-reduction gather over fp8 F, 4-batch-per-block index-amortized
//   final : exact fp32 last step (+ fused s3b).

#define T_STEPS 2048
#define BATCH 64
#define IN_W 256
#define SW 512
#define EPS 1e-5f
#define NCHUNK 64
#define CLEN 32
#define QSTEP 32
#define NQ 65

typedef __bf16 bf16x8 __attribute__((ext_vector_type(8)));
typedef float f32x4 __attribute__((ext_vector_type(4)));

__device__ __forceinline__ unsigned short bf16bits(float v) {
  __hip_bfloat16 h = __float2bfloat16(v);
  return *reinterpret_cast<unsigned short*>(&h);
}

__device__ __forceinline__ float bf16val(unsigned short u) {
  unsigned int x = ((unsigned int)u) << 16;
  return __uint_as_float(x);
}

// float -> OCP e4m3 via HW v_cvt_pk_fp8_f32 (RNE, saturating)
__device__ __forceinline__ unsigned char f8cvt(float v) {
  return (unsigned char)(__builtin_amdgcn_cvt_pk_fp8_f32(v, v, 0, false) & 0xff);
}
// e4m3 byte -> float via HW v_cvt_f32_fp8
__device__ __forceinline__ float f8val(unsigned char u) {
  return __builtin_amdgcn_cvt_f32_fp8((int)u, 0);
}

__device__ __forceinline__ void gload_lds16(const void* g, const void* l) {
  __builtin_amdgcn_global_load_lds(
      (const __attribute__((address_space(1))) unsigned int*)(uintptr_t)g,
      (__attribute__((address_space(3))) unsigned int*)(uintptr_t)l, 16, 0, 0);
}

// ---------------- permutation power tables (doubling) ------------------------
__global__ __launch_bounds__(512) void k_tabA(const int* __restrict__ perm,
                                              int* __restrict__ FW, int* __restrict__ IDXI) {
  __shared__ int pl[SW], il[SW];
  int j = threadIdx.x;
  pl[j] = perm[j];
  __syncthreads();
  il[pl[j]] = j;
  __syncthreads();
  int f = j, iv = j;
  FW[j] = f; IDXI[j] = iv;
  for (int t = 1; t <= QSTEP; ++t) {
    f = pl[f]; iv = il[iv];
    FW[t * SW + j] = f; IDXI[t * SW + j] = iv;
  }
}

__global__ __launch_bounds__(512) void k_tabB(const int* __restrict__ FW, const int* __restrict__ IDXI,
                                              int* __restrict__ FWQ, int* __restrict__ IDXIQ) {
  __shared__ int f32r[SW], i32r[SW];
  int j = threadIdx.x;
  f32r[j] = FW[QSTEP * SW + j];
  i32r[j] = IDXI[QSTEP * SW + j];
  __syncthreads();
  int f = j, iv = j;
  FWQ[j] = f; IDXIQ[j] = iv;
  for (int q = 1; q < NQ; ++q) {
    f = f32r[f]; iv = i32r[iv];
    FWQ[q * SW + j] = f; IDXIQ[q * SW + j] = iv;
  }
}

__global__ __launch_bounds__(512) void k_tabC(const int* __restrict__ FWQ, const int* __restrict__ IDXIQ,
                                              int* __restrict__ FW, int* __restrict__ IDXI) {
  int t = blockIdx.x;
  if (t <= QSTEP) return;
  int j = threadIdx.x;
  int q = t >> 5, r = t & 31;
  int a = FW[r * SW + j];
  FW[(size_t)t * SW + j] = FWQ[q * SW + a];
  int b = IDXI[r * SW + j];
  IDXI[(size_t)t * SW + j] = IDXIQ[q * SW + b];
}

// IDXI (int) -> IDXI16 (ushort): 2.1 MB table, fully L2-resident
__global__ __launch_bounds__(512) void k_tab16(const int* __restrict__ IDXI,
                                               unsigned short* __restrict__ IDXI16) {
  size_t i = (size_t)blockIdx.x * 512 + threadIdx.x;
  IDXI16[i] = (unsigned short)IDXI[i];
}

// ---------------- weights: W1 -> fp8 (HW cvt), W2 -> bf16 --------------------
__global__ __launch_bounds__(256) void k_wcast(const float* __restrict__ W1,
                                               const float* __restrict__ W2,
                                               unsigned char* __restrict__ W1q,
                                               __hip_bfloat16* __restrict__ W2b) {
  int i = blockIdx.x * 256 + threadIdx.x;
  if (i < SW * SW) W1q[i] = f8cvt(W1[i]);
  else W2b[i - SW * SW] = __float2bfloat16(W2[i - SW * SW]);
}

// ---------------- stage 1a: chunk sums, 4-batch index-amortized gather -------
// grid (NCHUNK, BATCH/4); 8-deep staging [8 t][4 b][256] = 32KB.
__global__ __launch_bounds__(512) void k_s1a(const float* __restrict__ x,
                                             const unsigned short* __restrict__ IDXI16,
                                             float* __restrict__ P1) {
  __shared__ float xs[8][4][IN_W] __attribute__((aligned(16)));
  int c = blockIdx.x, b0 = blockIdx.y * 4, tid = threadIdx.x;
  float acc[4] = {0.f, 0.f, 0.f, 0.f};
  int t0 = c * CLEN;
  for (int tt = 0; tt < CLEN; tt += 8) {
#pragma unroll
    for (int s = 0; s < 4; ++s) {
      int idx = s * 512 + tid;          // 2048 float4 granules
      int row = idx >> 8;               // t-row 0..7
      int rem = idx & 255;              // 4 b x 64 granules
      int bb = rem >> 6, col = (rem & 63) * 4;
      *reinterpret_cast<f32x4*>(&xs[row][bb][col]) =
          *reinterpret_cast<const f32x4*>(
              &x[((size_t)(t0 + tt + row) * BATCH + b0 + bb) * IN_W + col]);
    }
    __syncthreads();
#pragma unroll
    for (int k = 0; k < 8; ++k) {
      int i0 = IDXI16[(size_t)(t0 + tt + k) * SW + tid];
      if (i0 < IN_W) {
#pragma unroll
        for (int bb = 0; bb < 4; ++bb) acc[bb] += xs[k][bb][i0];
      }
    }
    __syncthreads();
  }
#pragma unroll
  for (int bb = 0; bb < 4; ++bb)
    P1[((size_t)c * BATCH + b0 + bb) * SW + tid] = acc[bb];
}

// ---------------- stage 1b: chunk scan, 16-deep batched loads ----------------
__global__ __launch_bounds__(512) void k_s1b(const float* __restrict__ init,
                                             float* __restrict__ P1) {
  int b = blockIdx.x, i = threadIdx.x;
  float run = EPS * init[i];
  float v[16];
  for (int g = 0; g < NCHUNK / 16; ++g) {
#pragma unroll
    for (int k = 0; k < 16; ++k)
      v[k] = P1[((size_t)(g * 16 + k) * BATCH + b) * SW + i];
#pragma unroll
    for (int k = 0; k < 16; ++k) {
      P1[((size_t)(g * 16 + k) * BATCH + b) * SW + i] = run;
      run += v[k];
    }
  }
}

// ---------------- stage 1c: prefix walk -> fp8 U + fp32 ULAST (r18) ----------
__global__ __launch_bounds__(512) void k_s1c(const float* __restrict__ x,
                                             const unsigned short* __restrict__ IDXI16,
                                             const float* __restrict__ P1,
                                             unsigned char* __restrict__ U,
                                             float* __restrict__ ULAST) {
  __shared__ float xs[16][IN_W] __attribute__((aligned(16)));
  __shared__ unsigned char us[16][SW] __attribute__((aligned(16)));
  __shared__ float ul[SW] __attribute__((aligned(16)));
  int c = blockIdx.x, b = blockIdx.y, tid = threadIdx.x;
  float v = P1[((size_t)c * BATCH + b) * SW + tid];
  int t0 = c * CLEN;
  int cur = IDXI16[(size_t)t0 * SW + tid];
  for (int tt = 0; tt < CLEN; tt += 16) {
#pragma unroll
    for (int s = 0; s < 2; ++s) {
      int idx = s * 512 + tid;
      int row = idx >> 6, col = (idx & 63) * 4;
      *reinterpret_cast<f32x4*>(&xs[row][col]) =
          *reinterpret_cast<const f32x4*>(&x[((size_t)(t0 + tt + row) * BATCH + b) * IN_W + col]);
    }
    __syncthreads();
#pragma unroll
    for (int k = 0; k < 16; ++k) {
      int t = t0 + tt + k;
      int nxt = IDXI16[(size_t)(t + 1) * SW + tid];
      if (cur < IN_W) v += xs[k][cur];
      us[k][nxt] = f8cvt(v);
      if (t == T_STEPS - 1) ul[nxt] = v;
      cur = nxt;
    }
    __syncthreads();
    {  // dump 16 rows x 512 fp8 = 512 int4, 1 per thread
      int row = tid >> 5, g = tid & 31;
      *reinterpret_cast<int4*>(U + ((size_t)(t0 + tt + row) * BATCH + b) * SW + g * 16) =
          *reinterpret_cast<const int4*>(&us[row][g * 16]);
    }
    __syncthreads();
  }
  if (c == NCHUNK - 1) ULAST[(size_t)b * SW + tid] = ul[tid];
}

// ---------------- FUSED MLP (round-17 verbatim, frozen) ----------------------
__global__ __launch_bounds__(512, 2) void k_mlp(const unsigned char* __restrict__ A,
                                                const unsigned char* __restrict__ W1,
                                                const __hip_bfloat16* __restrict__ W2,
                                                const float* __restrict__ b1,
                                                const float* __restrict__ b2,
                                                unsigned char* __restrict__ Fout) {
  __shared__ unsigned char smem[81920] __attribute__((aligned(16)));
  const int tid = threadIdx.x;
  const int lane = tid & 63;
  const int wv = tid >> 6;
  const int hwr = wv >> 1, hwc = wv & 1;   // phase-1 grid 4x2 (32x64 tiles)
  const int fwr = wv >> 2, fwc = wv & 3;   // phase-2 grid 2x4 (64x32 tiles)
  const size_t m0 = (size_t)blockIdx.x * 128;
  unsigned short* Hs = reinterpret_cast<unsigned short*>(smem + 49152);

  f32x4 Facc[4][4][2];                     // [n-quarter][m][n]
#pragma unroll
  for (int q = 0; q < 4; ++q)
#pragma unroll
    for (int m = 0; m < 4; ++m)
#pragma unroll
      for (int n = 0; n < 2; ++n) Facc[q][m][n] = (f32x4)0.f;

  for (int hb = 0; hb < 4; ++hb) {
    f32x4 Hacc[2][4];
#pragma unroll
    for (int m = 0; m < 2; ++m)
#pragma unroll
      for (int n = 0; n < 4; ++n) Hacc[m][n] = (f32x4)0.f;

    // ---- phase 1 (fp8): depth-3 pipeline, 2 loads/thread/stage ----
    auto stage1 = [&](int kt, int buf) {
      int row = tid >> 2, pg = tid & 3;
      int sg = pg ^ ((row >> 2) & 3);
      gload_lds16(A + (m0 + row) * 512 + kt * 64 + sg * 16,
                  (const char*)smem + buf * 8192 + tid * 16);
      gload_lds16(W1 + (size_t)(hb * 128 + row) * 512 + kt * 64 + sg * 16,
                  (const char*)smem + 24576 + buf * 8192 + tid * 16);
    };
    stage1(0, 0);
    stage1(1, 1);
#pragma unroll
    for (int kt = 0; kt < 8; ++kt) {
      if (kt < 7) asm volatile("s_waitcnt vmcnt(2)" ::: "memory");
      else        asm volatile("s_waitcnt vmcnt(0)" ::: "memory");
      __builtin_amdgcn_s_barrier();
      if (kt < 6) stage1(kt + 2, (kt + 2) % 3);
      const unsigned char* Ab = smem + (kt % 3) * 8192;
      const unsigned char* W1b_ = smem + 24576 + (kt % 3) * 8192;
#pragma unroll
      for (int kh = 0; kh < 2; ++kh) {
        long af[2], bfw[4];
        int g = kh * 4 + (lane >> 4);
#pragma unroll
        for (int m = 0; m < 2; ++m) {
          int row = hwr * 32 + m * 16 + (lane & 15);
          int off = row * 64 + ((((g >> 1) ^ ((row >> 2) & 3)) << 4) | ((g & 1) << 3));
          af[m] = *reinterpret_cast<const long*>(Ab + off);
        }
#pragma unroll
        for (int n = 0; n < 4; ++n) {
          int row = hwc * 64 + n * 16 + (lane & 15);
          int off = row * 64 + ((((g >> 1) ^ ((row >> 2) & 3)) << 4) | ((g & 1) << 3));
          bfw[n] = *reinterpret_cast<const long*>(W1b_ + off);
        }
#pragma unroll
        for (int m = 0; m < 2; ++m)
#pragma unroll
          for (int n = 0; n < 4; ++n)
            Hacc[m][n] = __builtin_amdgcn_mfma_f32_16x16x32_fp8_fp8(af[m], bfw[n], Hacc[m][n], 0, 0, 0);
      }
    }
    __syncthreads();  // all phase-1 LDS reads done

    // issue W2 round-0 (128 N-rows x 64 k bf16 = 16KB) into W2 buf 0 [0,16K)
    {
#pragma unroll
      for (int s = 0; s < 2; ++s) {
        int idx = s * 512 + tid;          // 1024 granules (128 rows x 8 of 16B)
        int row = idx >> 3, pg = idx & 7;
        int sg = pg ^ (row & 7);
        gload_lds16(W2 + (size_t)row * 512 + hb * 128 + sg * 8,
                    (const char*)smem + idx * 16);
      }
    }

    // Hacc + b1 -> relu -> bf16 Hs [128 rows][16 granules], phys = hg^(row&15)
    {
      const int rl = (lane >> 4) * 4;
      const int cl = lane & 15;
#pragma unroll
      for (int m = 0; m < 2; ++m)
#pragma unroll
        for (int n = 0; n < 4; ++n) {
          int coll = hwc * 64 + n * 16 + cl;
          float bv = b1[hb * 128 + coll];
#pragma unroll
          for (int r = 0; r < 4; ++r) {
            int rowl = hwr * 32 + m * 16 + rl + r;
            float h = Hacc[m][n][r] + bv;
            h = h > 0.f ? h : 0.f;
            int phys = (coll >> 3) ^ (rowl & 15);
            Hs[rowl * 128 + phys * 8 + (coll & 7)] = bf16bits(h);
          }
        }
    }
    __syncthreads();  // drains W2 round-0 + Hs writes

    // ---- phase 2 (bf16): 8 rounds r=(nh2=r>>1, ks=r&1), W2 tri-buffer ----
#pragma unroll
    for (int r = 0; r < 8; ++r) {
      if (r < 7) {
        int rn = r + 1;
        int nh2n = rn >> 1, ksn = rn & 1;
        int regbyte = (rn % 3) * 16384;
#pragma unroll
        for (int s = 0; s < 2; ++s) {
          int idx = s * 512 + tid;
          int row = idx >> 3, pg = idx & 7;
          int sg = pg ^ (row & 7);
          gload_lds16(W2 + (size_t)(nh2n * 128 + row) * 512 + hb * 128 + ksn * 64 + sg * 8,
                      (const char*)smem + regbyte + idx * 16);
        }
      }
      if (r > 0) {
        if (r < 7) asm volatile("s_waitcnt vmcnt(2)" ::: "memory");
        else       asm volatile("s_waitcnt vmcnt(0)" ::: "memory");
        __builtin_amdgcn_s_barrier();
      }
      const int nh2 = r >> 1, ks = r & 1;
      const unsigned short* w2b =
          reinterpret_cast<const unsigned short*>(smem + (r % 3) * 16384);
#pragma unroll
      for (int kh = 0; kh < 2; ++kh) {
        bf16x8 afH[4], bf2[2];
#pragma unroll
        for (int m = 0; m < 4; ++m) {
          int row = fwr * 64 + m * 16 + (lane & 15);
          int hg = ks * 8 + kh * 4 + (lane >> 4);
          int phys = hg ^ (row & 15);
          afH[m] = *reinterpret_cast<const bf16x8*>(&Hs[row * 128 + phys * 8]);
        }
#pragma unroll
        for (int n = 0; n < 2; ++n) {
          int row = fwc * 32 + n * 16 + (lane & 15);   // N within 128-quarter
          int lg = kh * 4 + (lane >> 4);
          int phys = lg ^ (row & 7);
          bf2[n] = *reinterpret_cast<const bf16x8*>(&w2b[row * 64 + phys * 8]);
        }
#pragma unroll
        for (int m = 0; m < 4; ++m)
#pragma unroll
          for (int n = 0; n < 2; ++n)
            Facc[nh2][m][n] = __builtin_amdgcn_mfma_f32_16x16x32_bf16(afH[m], bf2[n], Facc[nh2][m][n], 0, 0, 0);
      }
    }
    __syncthreads();  // phase-2 LDS reads done before next hb / epilogue
  }

  // ---- F epilogue (fp8): Facc + b2 -> scratch [128][256B] -> int2 stores ----
  const int rl = (lane >> 4) * 4;
  const int cl = lane & 15;
#pragma unroll
  for (int p = 0; p < 2; ++p) {      // col halves: quarters {2p, 2p+1}
#pragma unroll
    for (int qh = 0; qh < 2; ++qh) {
      int q = 2 * p + qh;
#pragma unroll
      for (int m = 0; m < 4; ++m)
#pragma unroll
        for (int n = 0; n < 2; ++n) {
          int coll = qh * 128 + fwc * 32 + n * 16 + cl;   // byte col within 256
          float bv = b2[p * 256 + coll];
#pragma unroll
          for (int r = 0; r < 4; ++r) {
            int rowl = fwr * 64 + m * 16 + rl + r;
            float v = Facc[q][m][n][r] + bv;
            int phys = (coll >> 3) ^ (rowl & 31);         // 32 8B-granules/row
            smem[rowl * 256 + phys * 8 + (coll & 7)] = f8cvt(v);
          }
        }
    }
    __syncthreads();
#pragma unroll
    for (int s = 0; s < 8; ++s) {
      int idx = s * 512 + tid;                            // 4096 = 128r x 32g
      int rowl = idx >> 5, g = idx & 31;
      int phys = g ^ (rowl & 31);
      *reinterpret_cast<int2*>(Fout + (m0 + rowl) * 512 + p * 256 + g * 8) =
          *reinterpret_cast<const int2*>(smem + rowl * 256 + phys * 8);
    }
    __syncthreads();
  }
}

// ---------------- stage 3a: 4-batch index-amortized gather (fp8 F) -----------
// grid (NCHUNK[-1], BATCH/4); 16-deep staging [16 t][4 b][512] fp8 = 32KB.
template <int LAST>
__global__ __launch_bounds__(512) void k_s3a(const unsigned char* __restrict__ F,
                                             const unsigned short* __restrict__ IDXI16,
                                             float* __restrict__ P3) {
  __shared__ unsigned char fs[16][4][SW] __attribute__((aligned(16)));
  int c = LAST ? (NCHUNK - 1) : blockIdx.x;
  int b0 = blockIdx.y * 4, tid = threadIdx.x;
  float acc[4] = {0.f, 0.f, 0.f, 0.f};
  int t0 = c * CLEN;
  for (int tt = 0; tt < CLEN; tt += 16) {
#pragma unroll
    for (int s = 0; s < 4; ++s) {
      int idx = s * 512 + tid;          // 2048 granules of 16B
      int row = idx >> 7;               // t-row 0..15
      int rem = idx & 127;              // 4 b x 32 granules
      int bb = rem >> 5, g = rem & 31;
      *reinterpret_cast<int4*>(&fs[row][bb][g * 16]) =
          *reinterpret_cast<const int4*>(
              &F[((size_t)(t0 + tt + row) * BATCH + b0 + bb) * SW + g * 16]);
    }
    __syncthreads();
    if (LAST) {
#pragma unroll
      for (int k = 0; k < 16; ++k) {
        int t = t0 + tt + k;
        if (t < T_STEPS - 1) {
          int i0 = IDXI16[(size_t)t * SW + tid];
#pragma unroll
          for (int bb = 0; bb < 4; ++bb) acc[bb] += f8val(fs[k][bb][i0]);
        }
      }
    } else {
#pragma unroll
      for (int k = 0; k < 16; ++k) {
        int i0 = IDXI16[(size_t)(t0 + tt + k) * SW + tid];
#pragma unroll
        for (int bb = 0; bb < 4; ++bb) acc[bb] += f8val(fs[k][bb][i0]);
      }
    }
    __syncthreads();
  }
#pragma unroll
  for (int bb = 0; bb < 4; ++bb)
    P3[((size_t)c * BATCH + b0 + bb) * SW + tid] = acc[bb];
}

// ---------------- exact fp32 final step (+ fused s3b) ------------------------
__global__ __launch_bounds__(512) void k_final(const float* __restrict__ P3,
                                               const int* __restrict__ FW,
                                               const float* __restrict__ ULAST,
                                               const float* __restrict__ W1,
                                               const float* __restrict__ b1,
                                               const float* __restrict__ W2,
                                               const float* __restrict__ b2,
                                               float* __restrict__ out) {
  __shared__ float ml[SW] __attribute__((aligned(16)));
  __shared__ float uc[SW] __attribute__((aligned(16)));
  __shared__ float hh[SW] __attribute__((aligned(16)));
  int b = blockIdx.x, j = threadIdx.x;
  float s = 0.f;
  for (int c = 0; c < NCHUNK; ++c) s += P3[((size_t)c * BATCH + b) * SW + j];
  ml[j] = s;
  __syncthreads();
  float e = ml[FW[(size_t)(T_STEPS - 1) * SW + j]];
  float u = ULAST[(size_t)b * SW + j] + EPS * e;
  uc[j] = u;
  __syncthreads();
  float pre = b1[j];
  {
    const f32x4* wr = (const f32x4*)(W1 + (size_t)j * SW);
    const f32x4* uv = (const f32x4*)uc;
    for (int k = 0; k < SW / 4; ++k) {
      f32x4 wv = wr[k], vv = uv[k];
      pre += wv[0] * vv[0] + wv[1] * vv[1] + wv[2] * vv[2] + wv[3] * vv[3];
    }
  }
  hh[j] = pre > 0.f ? pre : 0.f;
  __syncthreads();
  float d = b2[j];
  {
    const f32x4* wr = (const f32x4*)(W2 + (size_t)j * SW);
    const f32x4* hv = (const f32x4*)hh;
    for (int k = 0; k < SW / 4; ++k) {
      f32x4 wv = wr[k], vv = hv[k];
      d += wv[0] * vv[0] + wv[1] * vv[1] + wv[2] * vv[2] + wv[3] * vv[3];
    }
  }
  float sT = u + EPS * d;
  out[BATCH * 128 + (size_t)b * SW + j] = sT;                // last  [64,512]
  if (j >= SW - 128) out[b * 128 + (j - (SW - 128))] = sT;   // outputs [64,128]
}

// ---------------- host -------------------------------------------------------
extern "C" void kernel_launch(void* const* d_in, const int* in_sizes, int n_in,
                              void* d_out, int out_size, void* d_ws, size_t ws_size,
                              hipStream_t stream) {
  const float* x = (const float*)d_in[0];
  const float* init = (const float*)d_in[1];
  const float* W1 = (const float*)d_in[2];
  const float* b1 = (const float*)d_in[3];
  const float* W2 = (const float*)d_in[4];
  const float* b2 = (const float*)d_in[5];
  const int* perm = (const int*)d_in[6];
  float* out = (float*)d_out;

  char* w = (char*)d_ws;
  size_t off = 0;
  auto alloc = [&](size_t bytes) {
    size_t o = off;
    off = (off + bytes + 255) & ~(size_t)255;
    return o;
  };
  size_t oFW   = alloc((size_t)(T_STEPS + 1) * SW * 4);
  size_t oIDXI = alloc((size_t)(T_STEPS + 1) * SW * 4);
  size_t oI16  = alloc((size_t)(T_STEPS + 1) * SW * 2);
  size_t oFWQ  = alloc((size_t)NQ * SW * 4);
  size_t oIDXQ = alloc((size_t)NQ * SW * 4);
  size_t oW1q  = alloc((size_t)SW * SW);
  size_t oW2b  = alloc((size_t)SW * SW * 2);
  size_t oU    = alloc((size_t)T_STEPS * BATCH * SW);      // fp8
  size_t oF    = alloc((size_t)T_STEPS * BATCH * SW);      // fp8
  size_t oP1   = alloc((size_t)NCHUNK * BATCH * SW * 4);
  size_t oP3   = alloc((size_t)NCHUNK * BATCH * SW * 4);
  size_t oUL   = alloc((size_t)BATCH * SW * 4);
  if (off > ws_size) return;

  int* FW = (int*)(w + oFW);
  int* IDXI = (int*)(w + oIDXI);
  unsigned short* IDXI16 = (unsigned short*)(w + oI16);
  int* FWQ = (int*)(w + oFWQ);
  int* IDXIQ = (int*)(w + oIDXQ);
  unsigned char* W1q = (unsigned char*)(w + oW1q);
  __hip_bfloat16* W2b = (__hip_bfloat16*)(w + oW2b);
  unsigned char* U = (unsigned char*)(w + oU);
  unsigned char* F = (unsigned char*)(w + oF);
  float* P1 = (float*)(w + oP1);
  float* P3 = (float*)(w + oP3);
  float* ULAST = (float*)(w + oUL);

  k_tabA<<<1, 512, 0, stream>>>(perm, FW, IDXI);
  k_tabB<<<1, 512, 0, stream>>>(FW, IDXI, FWQ, IDXIQ);
  k_tabC<<<T_STEPS + 1, 512, 0, stream>>>(FWQ, IDXIQ, FW, IDXI);
  k_tab16<<<T_STEPS + 1, 512, 0, stream>>>(IDXI, IDXI16);
  k_wcast<<<(2 * SW * SW + 255) / 256, 256, 0, stream>>>(W1, W2, W1q, W2b);

  k_s1a<<<dim3(NCHUNK, BATCH / 4), 512, 0, stream>>>(x, IDXI16, P1);
  k_s1b<<<BATCH, 512, 0, stream>>>(init, P1);
  k_s1c<<<dim3(NCHUNK, BATCH), 512, 0, stream>>>(x, IDXI16, P1, U, ULAST);

  k_mlp<<<(T_STEPS * BATCH) / 128, 512, 0, stream>>>(U, W1q, W2b, b1, b2, F);

  k_s3a<0><<<dim3(NCHUNK - 1, BATCH / 4), 512, 0, stream>>>(F, IDXI16, P3);
  k_s3a<1><<<dim3(1, BATCH / 4), 512, 0, stream>>>(F, IDXI16, P3);

  k_final<<<BATCH, 512, 0, stream>>>(P3, FW, ULAST, W1, b1, W2, b2, out);
}